// Round 1
// baseline (1146.555 us; speedup 1.0000x reference)
//
#include <hip/hip_runtime.h>

#define NN   3000
#define EE   48000
#define KK1  1500
#define KK2  750
#define HIDC 64

// ---------------- kernels ----------------

__global__ void k_scatter_edges(const int* __restrict__ ei, float* __restrict__ T0) {
    int e = blockIdx.x * blockDim.x + threadIdx.x;
    if (e >= EE) return;
    int s = ei[e];        // edge_index[0][e] (source)
    int t = ei[EE + e];   // edge_index[1][e] (target)
    // T0[t][s] = A0[s][t]
    atomicAdd(&T0[(size_t)t * NN + s], 1.0f);
}

// dinv[row] = rsqrt(rowsum(T) + 2)
__global__ void k_rowsum_dinv(const float* __restrict__ T, float* __restrict__ dinv, int n) {
    int row = blockIdx.x * (blockDim.x >> 6) + (threadIdx.x >> 6);
    int lane = threadIdx.x & 63;
    if (row >= n) return;
    const float* r = T + (size_t)row * n;
    float s = 0.0f;
    for (int c = lane; c < n; c += 64) s += r[c];
    for (int off = 32; off; off >>= 1) s += __shfl_down(s, off, 64);
    if (lane == 0) dinv[row] = rsqrtf(s + 2.0f);
}

// g[i,:] = dinv[i] * (h[i,:] @ W)   (IC<=64, OC<=64); block=64, grid=n
__global__ void k_xw_scale(const float* __restrict__ h, const float* __restrict__ W,
                           const float* __restrict__ dinv, float* __restrict__ g,
                           int n, int IC, int OC) {
    int row = blockIdx.x;
    int c = threadIdx.x;
    __shared__ float hr[64];
    if (c < IC) hr[c] = h[(size_t)row * IC + c];
    __syncthreads();
    if (c >= OC) return;
    float acc = 0.0f;
    for (int k = 0; k < IC; ++k) acc += hr[k] * W[k * OC + c];
    g[(size_t)row * OC + c] = dinv[row] * acc;
}

// out[t,:] = act( dinv[t] * ( sum_s T[t,s]*g[s,:] + 2*g[t,:] ) + b )
// wave per row; skip-zero via ballot. block=256 (4 rows), C<=64.
__global__ void k_gcn_agg(const float* __restrict__ T, const float* __restrict__ g,
                          const float* __restrict__ dinv, const float* __restrict__ bias,
                          float* __restrict__ out, int n, int C, int do_tanh) {
    int row = blockIdx.x * (blockDim.x >> 6) + (threadIdx.x >> 6);
    int lane = threadIdx.x & 63;
    if (row >= n) return;
    const float* tr = T + (size_t)row * n;
    float acc = (lane < C) ? 2.0f * g[(size_t)row * C + lane] : 0.0f;
    for (int s0 = 0; s0 < n; s0 += 64) {
        int s = s0 + lane;
        float v = (s < n) ? tr[s] : 0.0f;
        unsigned long long m = __ballot(v != 0.0f);
        while (m) {
            int b = __builtin_ctzll(m);
            m &= m - 1;
            float vv = __shfl(v, b, 64);
            if (lane < C) acc += vv * g[(size_t)(s0 + b) * C + lane];
        }
    }
    if (lane < C) {
        float o = dinv[row] * acc + bias[lane];
        out[(size_t)row * C + lane] = do_tanh ? tanhf(o) : o;
    }
}

// score[i] = tanh( (h[i,:] . p) * rsqrt(p.p) ); block=64, grid=n, h is n x 64
__global__ void k_score(const float* __restrict__ h, const float* __restrict__ p,
                        float* __restrict__ score, int n) {
    int row = blockIdx.x;
    int lane = threadIdx.x;
    float pv = p[lane];
    float hv = h[(size_t)row * HIDC + lane];
    float d = hv * pv, pp = pv * pv;
    for (int off = 32; off; off >>= 1) {
        d  += __shfl_down(d, off, 64);
        pp += __shfl_down(pp, off, 64);
    }
    if (lane == 0) score[row] = tanhf(d * rsqrtf(pp));
}

// exact jax.lax.top_k order: value desc, index asc. rank-count O(n^2).
__global__ void k_topk(const float* __restrict__ score, int* __restrict__ perm, int n, int k) {
    __shared__ float s[3008];
    for (int i = threadIdx.x; i < n; i += blockDim.x) s[i] = score[i];
    __syncthreads();
    int i = blockIdx.x * blockDim.x + threadIdx.x;
    if (i >= n) return;
    float si = s[i];
    int rank = 0;
    for (int j = 0; j < n; ++j) {
        float sj = s[j];
        rank += (sj > si) || (sj == si && j < i);
    }
    if (rank < k) perm[rank] = i;
}

// hp[i,:] = h[perm[i],:] * score[perm[i]]; block=64, grid=k
__global__ void k_pool(const float* __restrict__ h, const float* __restrict__ score,
                       const int* __restrict__ perm, float* __restrict__ hp) {
    int i = blockIdx.x;
    int c = threadIdx.x;
    int pi = perm[i];
    hp[(size_t)i * HIDC + c] = h[(size_t)pi * HIDC + c] * score[pi];
}

// Bcol[k, j] = B[k, perm[j]] with B = T (diag forced to 1). grid=(ceil(kk/256), n)
__global__ void k_bcol(const float* __restrict__ T, const int* __restrict__ perm,
                       float* __restrict__ Bcol, int n, int kk) {
    int j = blockIdx.x * blockDim.x + threadIdx.x;
    int k = blockIdx.y;
    if (j >= kk) return;
    int pj = perm[j];
    Bcol[(size_t)k * kk + j] = (k == pj) ? 1.0f : T[(size_t)k * n + pj];
}

// Tdst[i,j] = sum_k B[perm[i],k] * Bcol[k,j], diag 0. wave per output row.
// B row read from Tsrc with diag-forced-1. kk <= 1536 -> 24 j-chunks of 64.
__global__ void k_aug(const float* __restrict__ Tsrc, const int* __restrict__ perm,
                      const float* __restrict__ Bcol, float* __restrict__ Tdst,
                      int n, int kk) {
    int i = blockIdx.x * (blockDim.x >> 6) + (threadIdx.x >> 6);
    int lane = threadIdx.x & 63;
    if (i >= kk) return;
    int pi = perm[i];
    const float* br = Tsrc + (size_t)pi * n;
    float acc[24];
#pragma unroll
    for (int q = 0; q < 24; ++q) acc[q] = 0.0f;
    for (int k0 = 0; k0 < n; k0 += 64) {
        int k = k0 + lane;
        float v = (k < n) ? br[k] : 0.0f;
        if (k == pi) v = 1.0f;
        unsigned long long m = __ballot(v != 0.0f);
        while (m) {
            int b = __builtin_ctzll(m);
            m &= m - 1;
            float vv = __shfl(v, b, 64);
            const float* bc = Bcol + (size_t)(k0 + b) * kk;
#pragma unroll
            for (int q = 0; q < 24; ++q) {
                int j = q * 64 + lane;
                if (j < kk) acc[q] += vv * bc[j];
            }
        }
    }
#pragma unroll
    for (int q = 0; q < 24; ++q) {
        int j = q * 64 + lane;
        if (j < kk) Tdst[(size_t)i * kk + j] = (j == i) ? 0.0f : acc[q];
    }
}

// dst[perm[i],:] += src[i,:]; block=64, grid=k (perm entries distinct)
__global__ void k_scatter_add(float* __restrict__ dst, const float* __restrict__ src,
                              const int* __restrict__ perm, int k) {
    int i = blockIdx.x;
    int c = threadIdx.x;
    int pi = perm[i];
    dst[(size_t)pi * HIDC + c] += src[(size_t)i * HIDC + c];
}

// ---------------- launch ----------------

extern "C" void kernel_launch(void* const* d_in, const int* in_sizes, int n_in,
                              void* d_out, int out_size, void* d_ws, size_t ws_size,
                              hipStream_t stream) {
    const float* x   = (const float*)d_in[0];
    const int*   ei  = (const int*)d_in[1];
    const float* W0  = (const float*)d_in[2];
    const float* b0  = (const float*)d_in[3];
    const float* W1  = (const float*)d_in[4];
    const float* b1  = (const float*)d_in[5];
    const float* W2  = (const float*)d_in[6];
    const float* b2  = (const float*)d_in[7];
    const float* p1  = (const float*)d_in[8];
    const float* p2  = (const float*)d_in[9];
    const float* Wu0 = (const float*)d_in[10];
    const float* bu0 = (const float*)d_in[11];
    const float* Wu1 = (const float*)d_in[12];
    const float* bu1 = (const float*)d_in[13];
    float* out = (float*)d_out;

    // workspace layout (floats)
    float* fw   = (float*)d_ws;
    float* T0   = fw;                          // NN*NN
    float* T1   = T0 + (size_t)NN * NN;        // KK1*KK1
    float* T2   = T1 + (size_t)KK1 * KK1;      // KK2*KK2
    float* Bcol = T2 + (size_t)KK2 * KK2;      // NN*KK1 (reused smaller at lvl2)
    float* g    = Bcol + (size_t)NN * KK1;     // NN*HIDC
    float* res0 = g    + (size_t)NN * HIDC;    // NN*HIDC
    float* res1 = res0 + (size_t)NN * HIDC;    // KK1*HIDC
    float* hp   = res1 + (size_t)KK1 * HIDC;   // KK1*HIDC
    float* hp2  = hp   + (size_t)KK1 * HIDC;   // KK2*HIDC
    float* x2   = hp2  + (size_t)KK2 * HIDC;   // KK2*HIDC
    float* xu   = x2   + (size_t)KK2 * HIDC;   // KK1*HIDC
    float* sc1  = xu   + (size_t)KK1 * HIDC;   // NN
    float* sc2  = sc1  + NN;                   // KK1
    float* dinv0 = sc2 + KK1;                  // NN
    float* dinv1 = dinv0 + NN;                 // KK1
    float* dinv2 = dinv1 + KK1;                // KK2
    int* perm1 = (int*)(dinv2 + KK2);          // KK1
    int* perm2 = perm1 + KK1;                  // KK2
    size_t need = (size_t)((float*)(perm2 + KK2) - fw) * 4;
    if (ws_size < need) return;  // workspace too small: fail loudly rather than corrupt

    dim3 b64(64), b256(256);

    // A0 (transposed: T0[t,s]) from edge list
    hipMemsetAsync(T0, 0, (size_t)NN * NN * sizeof(float), stream);
    k_scatter_edges<<<dim3((EE + 255) / 256), b256, 0, stream>>>(ei, T0);

    // ---- GCN0 (level 0) -> res0
    k_rowsum_dinv<<<dim3((NN + 3) / 4), b256, 0, stream>>>(T0, dinv0, NN);
    k_xw_scale<<<dim3(NN), b64, 0, stream>>>(x, W0, dinv0, g, NN, 16, 64);
    k_gcn_agg<<<dim3((NN + 3) / 4), b256, 0, stream>>>(T0, g, dinv0, b0, res0, NN, 64, 1);

    // ---- pool 1: score on res0, topk K1, T1 = augment(T0)[perm1][:,perm1]
    k_score<<<dim3(NN), b64, 0, stream>>>(res0, p1, sc1, NN);
    k_topk<<<dim3((NN + 255) / 256), b256, 0, stream>>>(sc1, perm1, NN, KK1);
    k_pool<<<dim3(KK1), b64, 0, stream>>>(res0, sc1, perm1, hp);
    k_bcol<<<dim3((KK1 + 255) / 256, NN), b256, 0, stream>>>(T0, perm1, Bcol, NN, KK1);
    k_aug<<<dim3((KK1 + 3) / 4), b256, 0, stream>>>(T0, perm1, Bcol, T1, NN, KK1);

    // ---- GCN1 (level 1) -> res1
    k_rowsum_dinv<<<dim3((KK1 + 3) / 4), b256, 0, stream>>>(T1, dinv1, KK1);
    k_xw_scale<<<dim3(KK1), b64, 0, stream>>>(hp, W1, dinv1, g, KK1, 64, 64);
    k_gcn_agg<<<dim3((KK1 + 3) / 4), b256, 0, stream>>>(T1, g, dinv1, b1, res1, KK1, 64, 1);

    // ---- pool 2: score on res1, topk K2, T2 = augment(T1)[perm2][:,perm2]
    k_score<<<dim3(KK1), b64, 0, stream>>>(res1, p2, sc2, KK1);
    k_topk<<<dim3((KK1 + 255) / 256), b256, 0, stream>>>(sc2, perm2, KK1, KK2);
    k_pool<<<dim3(KK2), b64, 0, stream>>>(res1, sc2, perm2, hp2);
    k_bcol<<<dim3((KK2 + 255) / 256, KK1), b256, 0, stream>>>(T1, perm2, Bcol, KK1, KK2);
    k_aug<<<dim3((KK2 + 3) / 4), b256, 0, stream>>>(T1, perm2, Bcol, T2, KK1, KK2);

    // ---- GCN2 (deepest) -> x2
    k_rowsum_dinv<<<dim3((KK2 + 3) / 4), b256, 0, stream>>>(T2, dinv2, KK2);
    k_xw_scale<<<dim3(KK2), b64, 0, stream>>>(hp2, W2, dinv2, g, KK2, 64, 64);
    k_gcn_agg<<<dim3((KK2 + 3) / 4), b256, 0, stream>>>(T2, g, dinv2, b2, x2, KK2, 64, 1);

    // ---- up to level 1: res1 += scatter(perm2, x2); GCN(Wu0) -> xu
    k_scatter_add<<<dim3(KK2), b64, 0, stream>>>(res1, x2, perm2, KK2);
    k_xw_scale<<<dim3(KK1), b64, 0, stream>>>(res1, Wu0, dinv1, g, KK1, 64, 64);
    k_gcn_agg<<<dim3((KK1 + 3) / 4), b256, 0, stream>>>(T1, g, dinv1, bu0, xu, KK1, 64, 1);

    // ---- up to level 0: res0 += scatter(perm1, xu); GCN(Wu1) -> out (no tanh)
    k_scatter_add<<<dim3(KK1), b64, 0, stream>>>(res0, xu, perm1, KK1);
    k_xw_scale<<<dim3(NN), b64, 0, stream>>>(res0, Wu1, dinv0, g, NN, 64, 16);
    k_gcn_agg<<<dim3((NN + 3) / 4), b256, 0, stream>>>(T0, g, dinv0, bu1, out, NN, 16, 0);
}

// Round 2
// 481.952 us; speedup vs baseline: 2.3790x; 2.3790x over previous
//
#include <hip/hip_runtime.h>

#define NN   3000
#define EE   48000
#define KK1  1500
#define KK2  750
#define HIDC 64

#define CAP0 128
#define CAP1 768
#define CAP2 768

// ---------------- kernels ----------------

__global__ void k_scatter_edges(const int* __restrict__ ei, float* __restrict__ T0) {
    int e = blockIdx.x * blockDim.x + threadIdx.x;
    if (e >= EE) return;
    int s = ei[e];        // source
    int t = ei[EE + e];   // target
    atomicAdd(&T0[(size_t)t * NN + s], 1.0f);   // T0[t][s] = A0[s][t]
}

// CSR build: wave per row, ballot compaction (column-ascending, deterministic).
__global__ void k_csr_build(const float* __restrict__ T, int n, int m,
                            int* __restrict__ cols, float* __restrict__ vals,
                            int* __restrict__ cnt, int CAP) {
    int row = blockIdx.x * (blockDim.x >> 6) + (threadIdx.x >> 6);
    int lane = threadIdx.x & 63;
    if (row >= n) return;
    const float* r = T + (size_t)row * m;
    int base = 0;
    for (int c0 = 0; c0 < m; c0 += 64) {
        int c = c0 + lane;
        float v = (c < m) ? r[c] : 0.0f;
        unsigned long long mb = __ballot(v != 0.0f);
        if (v != 0.0f) {
            int idx = base + __popcll(mb & ((1ull << lane) - 1ull));
            if (idx < CAP) {
                cols[(size_t)row * CAP + idx] = c;
                vals[(size_t)row * CAP + idx] = v;
            }
        }
        base += __popcll(mb);
    }
    if (lane == 0) cnt[row] = base < CAP ? base : CAP;
}

// dinv[row] = rsqrt(sum(vals of row) + 2); wave per row
__global__ void k_csr_dinv(const float* __restrict__ vals, const int* __restrict__ cnt,
                           int CAP, float* __restrict__ dinv, int n) {
    int row = blockIdx.x * (blockDim.x >> 6) + (threadIdx.x >> 6);
    int lane = threadIdx.x & 63;
    if (row >= n) return;
    int nz = cnt[row];
    float s = 0.0f;
    for (int e = lane; e < nz; e += 64) s += vals[(size_t)row * CAP + e];
    for (int off = 32; off; off >>= 1) s += __shfl_down(s, off, 64);
    if (lane == 0) dinv[row] = rsqrtf(s + 2.0f);
}

// g[i,:] = dinv[i] * (h[i,:] @ W); block=64, grid=n
__global__ void k_xw_scale(const float* __restrict__ h, const float* __restrict__ W,
                           const float* __restrict__ dinv, float* __restrict__ g,
                           int n, int IC, int OC) {
    int row = blockIdx.x;
    int c = threadIdx.x;
    __shared__ float hr[64];
    if (c < IC) hr[c] = h[(size_t)row * IC + c];
    __syncthreads();
    if (c >= OC) return;
    float acc = 0.0f;
    for (int k = 0; k < IC; ++k) acc += hr[k] * W[k * OC + c];
    g[(size_t)row * OC + c] = dinv[row] * acc;
}

// out[t,:] = act( dinv[t] * ( sum_e val_e * g[col_e,:] + 2*g[t,:] ) + b )
// wave per row, lane = feature; 4-way unrolled independent loads.
__global__ void k_gcn_agg_csr(const int* __restrict__ cols, const float* __restrict__ vals,
                              const int* __restrict__ cnt, int CAP,
                              const float* __restrict__ g, const float* __restrict__ dinv,
                              const float* __restrict__ bias, float* __restrict__ out,
                              int n, int C, int do_tanh) {
    int row = blockIdx.x * (blockDim.x >> 6) + (threadIdx.x >> 6);
    int lane = threadIdx.x & 63;
    if (row >= n) return;
    int nz = cnt[row];
    const int*   rc = cols + (size_t)row * CAP;
    const float* rv = vals + (size_t)row * CAP;
    bool act = lane < C;
    float acc0 = act ? 2.0f * g[(size_t)row * C + lane] : 0.0f;
    float acc1 = 0.0f, acc2 = 0.0f, acc3 = 0.0f;
    int e = 0;
    for (; e + 4 <= nz; e += 4) {
        int   c0 = rc[e], c1 = rc[e + 1], c2 = rc[e + 2], c3 = rc[e + 3];
        float v0 = rv[e], v1 = rv[e + 1], v2 = rv[e + 2], v3 = rv[e + 3];
        if (act) {
            acc0 += v0 * g[(size_t)c0 * C + lane];
            acc1 += v1 * g[(size_t)c1 * C + lane];
            acc2 += v2 * g[(size_t)c2 * C + lane];
            acc3 += v3 * g[(size_t)c3 * C + lane];
        }
    }
    for (; e < nz; ++e)
        if (act) acc0 += rv[e] * g[(size_t)rc[e] * C + lane];
    if (act) {
        float o = dinv[row] * (acc0 + acc1 + acc2 + acc3) + bias[lane];
        out[(size_t)row * C + lane] = do_tanh ? tanhf(o) : o;
    }
}

// score[i] = tanh( (h[i,:] . p) * rsqrt(p.p) ); block=64, grid=n
__global__ void k_score(const float* __restrict__ h, const float* __restrict__ p,
                        float* __restrict__ score, int n) {
    int row = blockIdx.x;
    int lane = threadIdx.x;
    float pv = p[lane];
    float hv = h[(size_t)row * HIDC + lane];
    float d = hv * pv, pp = pv * pv;
    for (int off = 32; off; off >>= 1) {
        d  += __shfl_down(d, off, 64);
        pp += __shfl_down(pp, off, 64);
    }
    if (lane == 0) score[row] = tanhf(d * rsqrtf(pp));
}

// exact jax.lax.top_k order: value desc, index asc. rank-count O(n^2).
__global__ void k_topk(const float* __restrict__ score, int* __restrict__ perm, int n, int k) {
    __shared__ float s[3008];
    for (int i = threadIdx.x; i < n; i += blockDim.x) s[i] = score[i];
    __syncthreads();
    int i = blockIdx.x * blockDim.x + threadIdx.x;
    if (i >= n) return;
    float si = s[i];
    int rank = 0;
    for (int j = 0; j < n; ++j) {
        float sj = s[j];
        rank += (sj > si) || (sj == si && j < i);
    }
    if (rank < k) perm[rank] = i;
}

// hp[i,:] = h[perm[i],:] * score[perm[i]]; block=64, grid=k
__global__ void k_pool(const float* __restrict__ h, const float* __restrict__ score,
                       const int* __restrict__ perm, float* __restrict__ hp) {
    int i = blockIdx.x;
    int c = threadIdx.x;
    int pi = perm[i];
    hp[(size_t)i * HIDC + c] = h[(size_t)pi * HIDC + c] * score[pi];
}

__global__ void k_selpos(const int* __restrict__ perm, int* __restrict__ selpos, int k) {
    int j = blockIdx.x * blockDim.x + threadIdx.x;
    if (j < k) selpos[perm[j]] = j;
}

// Bcol[row][j] = B[row, perm[j]] off-diag entries, scattered from CSR (Bcol pre-zeroed)
__global__ void k_bcol_scatter(const int* __restrict__ cols, const float* __restrict__ vals,
                               const int* __restrict__ cnt, int CAP,
                               const int* __restrict__ selpos, float* __restrict__ Bcol, int kk) {
    int row = blockIdx.x;
    int nz = cnt[row];
    for (int e = threadIdx.x; e < nz; e += blockDim.x) {
        int c = cols[(size_t)row * CAP + e];
        if (c == row) continue;                 // diag forced to 1 separately
        int j = selpos[c];
        if (j >= 0) Bcol[(size_t)row * kk + j] = vals[(size_t)row * CAP + e];
    }
}

__global__ void k_bcol_diag(const int* __restrict__ perm, float* __restrict__ Bcol, int kk) {
    int j = blockIdx.x * blockDim.x + threadIdx.x;
    if (j < kk) Bcol[(size_t)perm[j] * kk + j] = 1.0f;
}

// Tdst[i][j] = sum_k B[perm[i],k] * Bcol[k][j]; diag of B forced to 1, diag of Tdst zeroed.
// One block per output row i; threads strided over j; nonzero list in LDS; 2-way j ILP.
__global__ void k_aug_csr(const int* __restrict__ perm,
                          const int* __restrict__ cols, const float* __restrict__ vals,
                          const int* __restrict__ cnt, int CAP,
                          const float* __restrict__ Bcol, float* __restrict__ Tdst, int kk) {
    __shared__ int   scol[CAP2];
    __shared__ float sval[CAP2];
    int i = blockIdx.x;
    int pi = perm[i];
    int nz = cnt[pi];
    for (int e = threadIdx.x; e < nz; e += blockDim.x) {
        int c = cols[(size_t)pi * CAP + e];
        scol[e] = c;
        sval[e] = (c == pi) ? 0.0f : vals[(size_t)pi * CAP + e];  // diag handled via Bcol[pi]
    }
    __syncthreads();
    for (int j0 = threadIdx.x; j0 < kk; j0 += 2 * blockDim.x) {
        int j1 = j0 + blockDim.x;
        bool h1 = j1 < kk;
        float a0 = Bcol[(size_t)pi * kk + j0];                    // diag term: 1 * B[pi, perm[j]]
        float a1 = h1 ? Bcol[(size_t)pi * kk + j1] : 0.0f;
        for (int e = 0; e < nz; ++e) {
            float v = sval[e];
            size_t base = (size_t)scol[e] * kk;
            a0 += v * Bcol[base + j0];
            if (h1) a1 += v * Bcol[base + j1];
        }
        Tdst[(size_t)i * kk + j0] = (j0 == i) ? 0.0f : a0;
        if (h1) Tdst[(size_t)i * kk + j1] = (j1 == i) ? 0.0f : a1;
    }
}

// dst[perm[i],:] += src[i,:]; block=64, grid=k (perm entries distinct)
__global__ void k_scatter_add(float* __restrict__ dst, const float* __restrict__ src,
                              const int* __restrict__ perm, int k) {
    int i = blockIdx.x;
    int c = threadIdx.x;
    int pi = perm[i];
    dst[(size_t)pi * HIDC + c] += src[(size_t)i * HIDC + c];
}

// ---------------- launch ----------------

extern "C" void kernel_launch(void* const* d_in, const int* in_sizes, int n_in,
                              void* d_out, int out_size, void* d_ws, size_t ws_size,
                              hipStream_t stream) {
    const float* x   = (const float*)d_in[0];
    const int*   ei  = (const int*)d_in[1];
    const float* W0  = (const float*)d_in[2];
    const float* b0  = (const float*)d_in[3];
    const float* W1  = (const float*)d_in[4];
    const float* b1  = (const float*)d_in[5];
    const float* W2  = (const float*)d_in[6];
    const float* b2  = (const float*)d_in[7];
    const float* p1  = (const float*)d_in[8];
    const float* p2  = (const float*)d_in[9];
    const float* Wu0 = (const float*)d_in[10];
    const float* bu0 = (const float*)d_in[11];
    const float* Wu1 = (const float*)d_in[12];
    const float* bu1 = (const float*)d_in[13];
    float* out = (float*)d_out;

    // ---- workspace layout (float units) ----
    float* fw = (float*)d_ws;
    size_t off = 0;
    float* T0   = fw + off; off += (size_t)NN * NN;        // 9,000,000
    float* T1   = fw + off; off += (size_t)KK1 * KK1;      // 2,250,000
    float* T2   = fw + off; off += (size_t)KK2 * KK2;      //   562,500
    float* REG  = fw + off; off += (size_t)NN * KK1;       // 4,500,000 (Bcol | {csr1, Bcol2})
    int*   cols0 = (int*)(fw + off); off += (size_t)NN * CAP0;
    float* vals0 = fw + off;         off += (size_t)NN * CAP0;
    int*   cols2 = (int*)(fw + off); off += (size_t)KK2 * CAP2;
    float* vals2 = fw + off;         off += (size_t)KK2 * CAP2;
    int*   cnt0  = (int*)(fw + off); off += NN;
    int*   cnt1  = (int*)(fw + off); off += KK1;
    int*   cnt2  = (int*)(fw + off); off += KK2 + 2;
    float* g     = fw + off; off += (size_t)NN * HIDC;
    float* res0  = fw + off; off += (size_t)NN * HIDC;
    float* res1  = fw + off; off += (size_t)KK1 * HIDC;
    float* hp    = fw + off; off += (size_t)KK1 * HIDC;
    float* hp2   = fw + off; off += (size_t)KK2 * HIDC;
    float* x2    = fw + off; off += (size_t)KK2 * HIDC;
    float* xu    = fw + off; off += (size_t)KK1 * HIDC;
    float* sc1   = fw + off; off += NN;
    float* sc2   = fw + off; off += KK1;
    float* dinv0 = fw + off; off += NN;
    float* dinv1 = fw + off; off += KK1;
    float* dinv2 = fw + off; off += KK2 + 2;
    int* perm1   = (int*)(fw + off); off += KK1;
    int* perm2   = (int*)(fw + off); off += KK2 + 2;
    int* selpos1 = (int*)(fw + off); off += NN;
    int* selpos2 = (int*)(fw + off); off += KK1;
    if (ws_size < off * sizeof(float)) return;

    // region aliases
    float* Bcol  = REG;                                    // NN*KK1 (phase 1)
    int*   cols1 = (int*)REG;                              // KK1*CAP1
    float* vals1 = REG + (size_t)KK1 * CAP1;               // KK1*CAP1
    float* Bcol2 = REG + 2 * (size_t)KK1 * CAP1;           // KK1*KK2

    dim3 b64(64), b256(256);

    // ---- A0 (transposed) dense, then CSR0
    hipMemsetAsync(T0, 0, (size_t)NN * NN * sizeof(float), stream);
    k_scatter_edges<<<dim3((EE + 255) / 256), b256, 0, stream>>>(ei, T0);
    k_csr_build<<<dim3((NN + 3) / 4), b256, 0, stream>>>(T0, NN, NN, cols0, vals0, cnt0, CAP0);
    k_csr_dinv<<<dim3((NN + 3) / 4), b256, 0, stream>>>(vals0, cnt0, CAP0, dinv0, NN);

    // ---- GCN0 -> res0
    k_xw_scale<<<dim3(NN), b64, 0, stream>>>(x, W0, dinv0, g, NN, 16, 64);
    k_gcn_agg_csr<<<dim3((NN + 3) / 4), b256, 0, stream>>>(cols0, vals0, cnt0, CAP0, g, dinv0, b0, res0, NN, 64, 1);

    // ---- pool 1
    k_score<<<dim3(NN), b64, 0, stream>>>(res0, p1, sc1, NN);
    k_topk<<<dim3((NN + 255) / 256), b256, 0, stream>>>(sc1, perm1, NN, KK1);
    k_pool<<<dim3(KK1), b64, 0, stream>>>(res0, sc1, perm1, hp);
    hipMemsetAsync(selpos1, 0xFF, NN * sizeof(int), stream);
    k_selpos<<<dim3((KK1 + 255) / 256), b256, 0, stream>>>(perm1, selpos1, KK1);
    hipMemsetAsync(Bcol, 0, (size_t)NN * KK1 * sizeof(float), stream);
    k_bcol_scatter<<<dim3(NN), b64, 0, stream>>>(cols0, vals0, cnt0, CAP0, selpos1, Bcol, KK1);
    k_bcol_diag<<<dim3((KK1 + 255) / 256), b256, 0, stream>>>(perm1, Bcol, KK1);
    k_aug_csr<<<dim3(KK1), b256, 0, stream>>>(perm1, cols0, vals0, cnt0, CAP0, Bcol, T1, KK1);

    // ---- CSR1 (aliases onto Bcol region — Bcol dead after k_aug_csr)
    k_csr_build<<<dim3((KK1 + 3) / 4), b256, 0, stream>>>(T1, KK1, KK1, cols1, vals1, cnt1, CAP1);
    k_csr_dinv<<<dim3((KK1 + 3) / 4), b256, 0, stream>>>(vals1, cnt1, CAP1, dinv1, KK1);

    // ---- GCN1 -> res1
    k_xw_scale<<<dim3(KK1), b64, 0, stream>>>(hp, W1, dinv1, g, KK1, 64, 64);
    k_gcn_agg_csr<<<dim3((KK1 + 3) / 4), b256, 0, stream>>>(cols1, vals1, cnt1, CAP1, g, dinv1, b1, res1, KK1, 64, 1);

    // ---- pool 2
    k_score<<<dim3(KK1), b64, 0, stream>>>(res1, p2, sc2, KK1);
    k_topk<<<dim3((KK1 + 255) / 256), b256, 0, stream>>>(sc2, perm2, KK1, KK2);
    k_pool<<<dim3(KK2), b64, 0, stream>>>(res1, sc2, perm2, hp2);
    hipMemsetAsync(selpos2, 0xFF, KK1 * sizeof(int), stream);
    k_selpos<<<dim3((KK2 + 255) / 256), b256, 0, stream>>>(perm2, selpos2, KK2);
    hipMemsetAsync(Bcol2, 0, (size_t)KK1 * KK2 * sizeof(float), stream);
    k_bcol_scatter<<<dim3(KK1), b64, 0, stream>>>(cols1, vals1, cnt1, CAP1, selpos2, Bcol2, KK2);
    k_bcol_diag<<<dim3((KK2 + 255) / 256), b256, 0, stream>>>(perm2, Bcol2, KK2);
    k_aug_csr<<<dim3(KK2), b256, 0, stream>>>(perm2, cols1, vals1, cnt1, CAP1, Bcol2, T2, KK2);

    // ---- CSR2 (CAP2=768 >= 750: lossless)
    k_csr_build<<<dim3((KK2 + 3) / 4), b256, 0, stream>>>(T2, KK2, KK2, cols2, vals2, cnt2, CAP2);
    k_csr_dinv<<<dim3((KK2 + 3) / 4), b256, 0, stream>>>(vals2, cnt2, CAP2, dinv2, KK2);

    // ---- GCN2 -> x2
    k_xw_scale<<<dim3(KK2), b64, 0, stream>>>(hp2, W2, dinv2, g, KK2, 64, 64);
    k_gcn_agg_csr<<<dim3((KK2 + 3) / 4), b256, 0, stream>>>(cols2, vals2, cnt2, CAP2, g, dinv2, b2, x2, KK2, 64, 1);

    // ---- up to level 1
    k_scatter_add<<<dim3(KK2), b64, 0, stream>>>(res1, x2, perm2, KK2);
    k_xw_scale<<<dim3(KK1), b64, 0, stream>>>(res1, Wu0, dinv1, g, KK1, 64, 64);
    k_gcn_agg_csr<<<dim3((KK1 + 3) / 4), b256, 0, stream>>>(cols1, vals1, cnt1, CAP1, g, dinv1, bu0, xu, KK1, 64, 1);

    // ---- up to level 0 -> out (no tanh)
    k_scatter_add<<<dim3(KK1), b64, 0, stream>>>(res0, xu, perm1, KK1);
    k_xw_scale<<<dim3(NN), b64, 0, stream>>>(res0, Wu1, dinv0, g, NN, 64, 16);
    k_gcn_agg_csr<<<dim3((NN + 3) / 4), b256, 0, stream>>>(cols0, vals0, cnt0, CAP0, g, dinv0, bu1, out, NN, 16, 0);
}

// Round 5
// 324.922 us; speedup vs baseline: 3.5287x; 1.4833x over previous
//
#include <hip/hip_runtime.h>

#define NN   3000
#define EE   48000
#define KK1  1500
#define KK2  750
#define KK2P 752      // padded row stride for T2 / Bcol2 (float4 alignment)
#define HIDC 64

#define CAP0 128
#define CAP1 768
#define CAP2 768
#define CAPMAX 768

// ---------------- kernels ----------------

__global__ void k_scatter_edges(const int* __restrict__ ei, float* __restrict__ T0) {
    int e = blockIdx.x * blockDim.x + threadIdx.x;
    if (e >= EE) return;
    int s = ei[e];        // source
    int t = ei[EE + e];   // target
    atomicAdd(&T0[(size_t)t * NN + s], 1.0f);   // T0[t][s] = A0[s][t]
}

// CSR build (ballot compaction, column-ascending) + fused dinv = rsqrt(rowsum+2).
// Row sum taken over the full scan (pre-truncation) — exact (integer values).
__global__ void k_csr_build(const float* __restrict__ T, int ld, int n, int m,
                            int* __restrict__ cols, float* __restrict__ vals,
                            int* __restrict__ cnt, int CAP, float* __restrict__ dinv) {
    int row = blockIdx.x * (blockDim.x >> 6) + (threadIdx.x >> 6);
    int lane = threadIdx.x & 63;
    if (row >= n) return;
    const float* r = T + (size_t)row * ld;
    int base = 0;
    float s = 0.0f;
    for (int c0 = 0; c0 < m; c0 += 64) {
        int c = c0 + lane;
        float v = (c < m) ? r[c] : 0.0f;
        unsigned long long mb = __ballot(v != 0.0f);
        if (v != 0.0f) {
            int idx = base + __popcll(mb & ((1ull << lane) - 1ull));
            if (idx < CAP) {
                cols[(size_t)row * CAP + idx] = c;
                vals[(size_t)row * CAP + idx] = v;
            }
            s += v;
        }
        base += __popcll(mb);
    }
    for (int off = 32; off; off >>= 1) s += __shfl_down(s, off, 64);
    if (lane == 0) {
        cnt[row] = base < CAP ? base : CAP;
        dinv[row] = rsqrtf(s + 2.0f);
    }
}

// g[i,:] = dinv[i] * ((h[i,:] + up[selpos[i],:]) @ W); block=64, grid=n
__global__ void k_xw_scale(const float* __restrict__ h, const float* __restrict__ up,
                           const int* __restrict__ selpos,
                           const float* __restrict__ W, const float* __restrict__ dinv,
                           float* __restrict__ g, int n, int IC, int OC) {
    int row = blockIdx.x;
    int c = threadIdx.x;
    __shared__ float hr[64];
    if (c < IC) {
        float v = h[(size_t)row * IC + c];
        if (selpos) {
            int sp = selpos[row];
            if (sp >= 0) v += up[(size_t)sp * IC + c];
        }
        hr[c] = v;
    }
    __syncthreads();
    if (c >= OC) return;
    float acc = 0.0f;
    for (int k = 0; k < IC; ++k) acc += hr[k] * W[k * OC + c];
    g[(size_t)row * OC + c] = dinv[row] * acc;
}

// out[t,:] = act( dinv[t] * ( sum_e val_e * g[col_e,:] + 2*g[t,:] ) + b )
// wave per row, lane = feature. Optional fused TopK score (requires C==64, do_tanh).
__global__ void k_gcn_agg_csr(const int* __restrict__ cols, const float* __restrict__ vals,
                              const int* __restrict__ cnt, int CAP,
                              const float* __restrict__ g, const float* __restrict__ dinv,
                              const float* __restrict__ bias, float* __restrict__ out,
                              int n, int C, int do_tanh,
                              const float* __restrict__ p, float* __restrict__ score) {
    int row = blockIdx.x * (blockDim.x >> 6) + (threadIdx.x >> 6);
    int lane = threadIdx.x & 63;
    if (row >= n) return;
    int nz = cnt[row];
    const int*   rc = cols + (size_t)row * CAP;
    const float* rv = vals + (size_t)row * CAP;
    bool act = lane < C;
    float acc0 = act ? 2.0f * g[(size_t)row * C + lane] : 0.0f;
    float acc1 = 0.0f, acc2 = 0.0f, acc3 = 0.0f;
    int e = 0;
    for (; e + 4 <= nz; e += 4) {
        int   c0 = rc[e], c1 = rc[e + 1], c2 = rc[e + 2], c3 = rc[e + 3];
        float v0 = rv[e], v1 = rv[e + 1], v2 = rv[e + 2], v3 = rv[e + 3];
        if (act) {
            acc0 += v0 * g[(size_t)c0 * C + lane];
            acc1 += v1 * g[(size_t)c1 * C + lane];
            acc2 += v2 * g[(size_t)c2 * C + lane];
            acc3 += v3 * g[(size_t)c3 * C + lane];
        }
    }
    for (; e < nz; ++e)
        if (act) acc0 += rv[e] * g[(size_t)rc[e] * C + lane];
    float o = 0.0f;
    if (act) {
        o = dinv[row] * (acc0 + acc1 + acc2 + acc3) + bias[lane];
        if (do_tanh) o = tanhf(o);
        out[(size_t)row * C + lane] = o;
    }
    if (p) {  // fused score = tanh((row . p) * rsqrt(p.p)); all 64 lanes live (C==64)
        float pv = p[lane];
        float d = o * pv, pp = pv * pv;
        for (int off = 32; off; off >>= 1) {
            d  += __shfl_down(d, off, 64);
            pp += __shfl_down(pp, off, 64);
        }
        if (lane == 0) score[row] = tanhf(d * rsqrtf(pp));
    }
}

// exact jax.lax.top_k order (value desc, index asc), rank-count.
// Block per candidate i; threads strided over j; coalesced L1-resident reads.
__global__ void k_topk(const float* __restrict__ score, int* __restrict__ perm, int n, int k) {
    int i = blockIdx.x;
    float si = score[i];
    int r = 0;
    for (int j = threadIdx.x; j < n; j += blockDim.x) {
        float sj = score[j];
        r += (sj > si) || (sj == si && j < i);
    }
    int lane = threadIdx.x & 63, wid = threadIdx.x >> 6;
    for (int off = 32; off; off >>= 1) r += __shfl_down(r, off, 64);
    __shared__ int red[4];
    if (lane == 0) red[wid] = r;
    __syncthreads();
    if (threadIdx.x == 0) {
        int rank = red[0] + red[1] + red[2] + red[3];
        if (rank < k) perm[rank] = i;
    }
}

// hp[i,:] = h[perm[i],:] * score[perm[i]]; also selpos[perm[i]] = i. block=64, grid=k
__global__ void k_pool(const float* __restrict__ h, const float* __restrict__ score,
                       const int* __restrict__ perm, float* __restrict__ hp,
                       int* __restrict__ selpos) {
    int i = blockIdx.x;
    int c = threadIdx.x;
    int pi = perm[i];
    hp[(size_t)i * HIDC + c] = h[(size_t)pi * HIDC + c] * score[pi];
    if (c == 0) selpos[pi] = i;
}

// Bcol[row][j] = B[row, perm[j]] (B = T with diag forced 1); Bcol pre-zeroed.
__global__ void k_bcol_scatter(const int* __restrict__ cols, const float* __restrict__ vals,
                               const int* __restrict__ cnt, int CAP,
                               const int* __restrict__ selpos, float* __restrict__ Bcol, int ldb) {
    int row = blockIdx.x;
    int nz = cnt[row];
    for (int e = threadIdx.x; e < nz; e += blockDim.x) {
        int c = cols[(size_t)row * CAP + e];
        if (c == row) continue;                 // diag handled below
        int j = selpos[c];
        if (j >= 0) Bcol[(size_t)row * ldb + j] = vals[(size_t)row * CAP + e];
    }
    if (threadIdx.x == 0) {
        int j = selpos[row];
        if (j >= 0) Bcol[(size_t)row * ldb + j] = 1.0f;  // B diag = 1
    }
}

// Tdst[i][j] = sum_k B[perm[i],k] * Bcol[k][j], diag(Tdst)=0.
// grid (rows, j-chunks); thread owns one float4 of j. CSR row staged in LDS.
__global__ void k_aug_csr(const int* __restrict__ perm,
                          const int* __restrict__ cols, const float* __restrict__ vals,
                          const int* __restrict__ cnt, int CAP,
                          const float* __restrict__ Bcol, int ldb,
                          float* __restrict__ Tdst, int ldt, int kk) {
    __shared__ int   scol[CAPMAX];
    __shared__ float sval[CAPMAX];
    int i = blockIdx.x;
    int pi = perm[i];
    int nz = cnt[pi];
    for (int e = threadIdx.x; e < nz; e += blockDim.x) {
        int c = cols[(size_t)pi * CAP + e];
        scol[e] = c;
        sval[e] = (c == pi) ? 0.0f : vals[(size_t)pi * CAP + e];  // diag via explicit Bcol[pi] term
    }
    __syncthreads();
    int j = (blockIdx.y * blockDim.x + threadIdx.x) * 4;
    if (j >= kk) return;
    int j4 = j >> 2;
    float4 a = ((const float4*)(Bcol + (size_t)pi * ldb))[j4];   // 1 * B[pi, perm[j..j+3]]
    for (int e = 0; e < nz; ++e) {
        float v = sval[e];
        float4 b = ((const float4*)(Bcol + (size_t)scol[e] * ldb))[j4];
        a.x += v * b.x; a.y += v * b.y; a.z += v * b.z; a.w += v * b.w;
    }
    if (i >= j && i < j + 4) ((float*)&a)[i - j] = 0.0f;         // zero output diag
    *(float4*)(Tdst + (size_t)i * ldt + j) = a;
}

// ---------------- launch ----------------

extern "C" void kernel_launch(void* const* d_in, const int* in_sizes, int n_in,
                              void* d_out, int out_size, void* d_ws, size_t ws_size,
                              hipStream_t stream) {
    const float* x   = (const float*)d_in[0];
    const int*   ei  = (const int*)d_in[1];
    const float* W0  = (const float*)d_in[2];
    const float* b0  = (const float*)d_in[3];
    const float* W1  = (const float*)d_in[4];
    const float* b1  = (const float*)d_in[5];
    const float* W2  = (const float*)d_in[6];
    const float* b2  = (const float*)d_in[7];
    const float* p1  = (const float*)d_in[8];
    const float* p2  = (const float*)d_in[9];
    const float* Wu0 = (const float*)d_in[10];
    const float* bu0 = (const float*)d_in[11];
    const float* Wu1 = (const float*)d_in[12];
    const float* bu1 = (const float*)d_in[13];
    float* out = (float*)d_out;

    // ---- workspace layout (float units; every chunk a multiple of 4 floats) ----
    float* fw = (float*)d_ws;
    size_t off = 0;
    float* T0   = fw + off; off += (size_t)NN * NN;        // 9,000,000
    float* T1   = fw + off; off += (size_t)KK1 * KK1;      // 2,250,000
    float* T2   = fw + off; off += (size_t)KK2 * KK2P;     //   564,000 (ld = 752)
    float* REG  = fw + off; off += (size_t)NN * KK1;       // 4,500,000 (Bcol | {csr1, Bcol2})
    int*   cols0 = (int*)(fw + off); off += (size_t)NN * CAP0;
    float* vals0 = fw + off;         off += (size_t)NN * CAP0;
    int*   cols2 = (int*)(fw + off); off += (size_t)KK2 * CAP2;
    float* vals2 = fw + off;         off += (size_t)KK2 * CAP2;
    int*   cnt0  = (int*)(fw + off); off += NN;
    int*   cnt1  = (int*)(fw + off); off += KK1;
    int*   cnt2  = (int*)(fw + off); off += KK2P;
    float* g     = fw + off; off += (size_t)NN * HIDC;
    float* res0  = fw + off; off += (size_t)NN * HIDC;
    float* res1  = fw + off; off += (size_t)KK1 * HIDC;
    float* hp    = fw + off; off += (size_t)KK1 * HIDC;
    float* hp2   = fw + off; off += (size_t)KK2 * HIDC;
    float* x2    = fw + off; off += (size_t)KK2 * HIDC;
    float* xu    = fw + off; off += (size_t)KK1 * HIDC;
    float* sc1   = fw + off; off += NN;
    float* sc2   = fw + off; off += KK1;
    float* dinv0 = fw + off; off += NN;
    float* dinv1 = fw + off; off += KK1;
    float* dinv2 = fw + off; off += KK2P;
    int* perm1   = (int*)(fw + off); off += KK1;
    int* perm2   = (int*)(fw + off); off += KK2P;
    int* selpos1 = (int*)(fw + off); off += NN;
    int* selpos2 = (int*)(fw + off); off += KK1;
    if (ws_size < off * sizeof(float)) return;

    // region aliases (lifetimes disjoint, stream-ordered)
    float* Bcol  = REG;                                    // NN x KK1      (pool-1 phase)
    int*   cols1 = (int*)REG;                              // KK1 x CAP1
    float* vals1 = REG + (size_t)KK1 * CAP1;               // KK1 x CAP1
    float* Bcol2 = REG + 2 * (size_t)KK1 * CAP1;           // KK1 x KK2P

    dim3 b64(64), b256(256);

    // ---- A0 (transposed) dense, then CSR0 (+dinv0)
    hipMemsetAsync(T0, 0, (size_t)NN * NN * sizeof(float), stream);
    k_scatter_edges<<<dim3((EE + 255) / 256), b256, 0, stream>>>(ei, T0);
    k_csr_build<<<dim3((NN + 3) / 4), b256, 0, stream>>>(T0, NN, NN, NN, cols0, vals0, cnt0, CAP0, dinv0);

    // ---- GCN0 -> res0 (+score sc1)
    k_xw_scale<<<dim3(NN), b64, 0, stream>>>(x, nullptr, nullptr, W0, dinv0, g, NN, 16, 64);
    k_gcn_agg_csr<<<dim3((NN + 3) / 4), b256, 0, stream>>>(cols0, vals0, cnt0, CAP0, g, dinv0, b0, res0, NN, 64, 1, p1, sc1);

    // ---- pool 1
    k_topk<<<dim3(NN), b256, 0, stream>>>(sc1, perm1, NN, KK1);
    hipMemsetAsync(selpos1, 0xFF, NN * sizeof(int), stream);
    k_pool<<<dim3(KK1), b64, 0, stream>>>(res0, sc1, perm1, hp, selpos1);
    hipMemsetAsync(Bcol, 0, (size_t)NN * KK1 * sizeof(float), stream);
    k_bcol_scatter<<<dim3(NN), b64, 0, stream>>>(cols0, vals0, cnt0, CAP0, selpos1, Bcol, KK1);
    k_aug_csr<<<dim3(KK1, 2), b256, 0, stream>>>(perm1, cols0, vals0, cnt0, CAP0, Bcol, KK1, T1, KK1, KK1);

    // ---- CSR1 (+dinv1) (aliases onto Bcol region — Bcol dead)
    k_csr_build<<<dim3((KK1 + 3) / 4), b256, 0, stream>>>(T1, KK1, KK1, KK1, cols1, vals1, cnt1, CAP1, dinv1);

    // ---- GCN1 -> res1 (+score sc2)
    k_xw_scale<<<dim3(KK1), b64, 0, stream>>>(hp, nullptr, nullptr, W1, dinv1, g, KK1, 64, 64);
    k_gcn_agg_csr<<<dim3((KK1 + 3) / 4), b256, 0, stream>>>(cols1, vals1, cnt1, CAP1, g, dinv1, b1, res1, KK1, 64, 1, p2, sc2);

    // ---- pool 2
    k_topk<<<dim3(KK1), b256, 0, stream>>>(sc2, perm2, KK1, KK2);
    hipMemsetAsync(selpos2, 0xFF, KK1 * sizeof(int), stream);
    k_pool<<<dim3(KK2), b64, 0, stream>>>(res1, sc2, perm2, hp2, selpos2);
    hipMemsetAsync(Bcol2, 0, (size_t)KK1 * KK2P * sizeof(float), stream);
    k_bcol_scatter<<<dim3(KK1), b64, 0, stream>>>(cols1, vals1, cnt1, CAP1, selpos2, Bcol2, KK2P);
    k_aug_csr<<<dim3(KK2, 1), b256, 0, stream>>>(perm2, cols1, vals1, cnt1, CAP1, Bcol2, KK2P, T2, KK2P, KK2);

    // ---- CSR2 (+dinv2) (CAP2=768 >= 750: lossless)
    k_csr_build<<<dim3((KK2 + 3) / 4), b256, 0, stream>>>(T2, KK2P, KK2, KK2, cols2, vals2, cnt2, CAP2, dinv2);

    // ---- GCN2 -> x2
    k_xw_scale<<<dim3(KK2), b64, 0, stream>>>(hp2, nullptr, nullptr, W2, dinv2, g, KK2, 64, 64);
    k_gcn_agg_csr<<<dim3((KK2 + 3) / 4), b256, 0, stream>>>(cols2, vals2, cnt2, CAP2, g, dinv2, b2, x2, KK2, 64, 1, nullptr, nullptr);

    // ---- up to level 1: h = res1 + up(x2 via selpos2); GCN(Wu0) -> xu
    k_xw_scale<<<dim3(KK1), b64, 0, stream>>>(res1, x2, selpos2, Wu0, dinv1, g, KK1, 64, 64);
    k_gcn_agg_csr<<<dim3((KK1 + 3) / 4), b256, 0, stream>>>(cols1, vals1, cnt1, CAP1, g, dinv1, bu0, xu, KK1, 64, 1, nullptr, nullptr);

    // ---- up to level 0: h = res0 + up(xu via selpos1); GCN(Wu1) -> out (no tanh)
    k_xw_scale<<<dim3(NN), b64, 0, stream>>>(res0, xu, selpos1, Wu1, dinv0, g, NN, 64, 16);
    k_gcn_agg_csr<<<dim3((NN + 3) / 4), b256, 0, stream>>>(cols0, vals0, cnt0, CAP0, g, dinv0, bu1, out, NN, 16, 0, nullptr, nullptr);
}

// Round 6
// 251.764 us; speedup vs baseline: 4.5541x; 1.2906x over previous
//
#include <hip/hip_runtime.h>

#define NN   3000
#define EE   48000
#define KK1  1500
#define KK2  750
#define KK2P 752      // padded row stride for T2 / Bcol2 (float4 alignment)
#define HIDC 64

#define CAP0 128
#define CAP1 768
#define CAP2 768
#define CAPMAX 768

// ---------------- kernels ----------------

__global__ void k_scatter_edges(const int* __restrict__ ei, float* __restrict__ T0) {
    int e = blockIdx.x * blockDim.x + threadIdx.x;
    if (e >= EE) return;
    int s = ei[e];        // source
    int t = ei[EE + e];   // target
    atomicAdd(&T0[(size_t)t * NN + s], 1.0f);   // T0[t][s] = A0[s][t]
}

// CSR build (ballot compaction, column-ascending) + fused dinv = rsqrt(rowsum+2).
__global__ void k_csr_build(const float* __restrict__ T, int ld, int n, int m,
                            int* __restrict__ cols, float* __restrict__ vals,
                            int* __restrict__ cnt, int CAP, float* __restrict__ dinv) {
    int row = blockIdx.x * (blockDim.x >> 6) + (threadIdx.x >> 6);
    int lane = threadIdx.x & 63;
    if (row >= n) return;
    const float* r = T + (size_t)row * ld;
    int base = 0;
    float s = 0.0f;
    for (int c0 = 0; c0 < m; c0 += 64) {
        int c = c0 + lane;
        float v = (c < m) ? r[c] : 0.0f;
        unsigned long long mb = __ballot(v != 0.0f);
        if (v != 0.0f) {
            int idx = base + __popcll(mb & ((1ull << lane) - 1ull));
            if (idx < CAP) {
                cols[(size_t)row * CAP + idx] = c;
                vals[(size_t)row * CAP + idx] = v;
            }
            s += v;
        }
        base += __popcll(mb);
    }
    for (int off = 32; off; off >>= 1) s += __shfl_down(s, off, 64);
    if (lane == 0) {
        cnt[row] = base < CAP ? base : CAP;
        dinv[row] = rsqrtf(s + 2.0f);
    }
}

// g[i,:] = dinv[i] * ((h[i,:] + up[selpos[i],:]) @ W); block=64, grid=n
__global__ void k_xw_scale(const float* __restrict__ h, const float* __restrict__ up,
                           const int* __restrict__ selpos,
                           const float* __restrict__ W, const float* __restrict__ dinv,
                           float* __restrict__ g, int n, int IC, int OC) {
    int row = blockIdx.x;
    int c = threadIdx.x;
    __shared__ float hr[64];
    if (c < IC) {
        float v = h[(size_t)row * IC + c];
        if (selpos) {
            int sp = selpos[row];
            if (sp >= 0) v += up[(size_t)sp * IC + c];
        }
        hr[c] = v;
    }
    __syncthreads();
    if (c >= OC) return;
    float acc = 0.0f;
    for (int k = 0; k < IC; ++k) acc += hr[k] * W[k * OC + c];
    g[(size_t)row * OC + c] = dinv[row] * acc;
}

// out[t,:] = act( dinv[t] * ( sum_e val_e * g[col_e,:] + 2*g[t,:] ) + b )
// Block per row (grid=n), 4 waves split the nonzero list (16-entry rounds, 4-ILP
// per wave), LDS reduce; wave 0 finishes + optional fused TopK score (C==64).
__global__ void k_gcn_agg_csr(const int* __restrict__ cols, const float* __restrict__ vals,
                              const int* __restrict__ cnt, int CAP,
                              const float* __restrict__ g, const float* __restrict__ dinv,
                              const float* __restrict__ bias, float* __restrict__ out,
                              int n, int C, int do_tanh,
                              const float* __restrict__ p, float* __restrict__ score) {
    int row = blockIdx.x;
    int w = threadIdx.x >> 6;
    int lane = threadIdx.x & 63;
    int nz = cnt[row];
    const int*   rc = cols + (size_t)row * CAP;
    const float* rv = vals + (size_t)row * CAP;
    bool act = lane < C;
    float a0 = 0.f, a1 = 0.f, a2 = 0.f, a3 = 0.f;
    for (int e = 4 * w; e + 4 <= nz; e += 16) {
        int   c0 = rc[e], c1 = rc[e + 1], c2 = rc[e + 2], c3 = rc[e + 3];
        float v0 = rv[e], v1 = rv[e + 1], v2 = rv[e + 2], v3 = rv[e + 3];
        if (act) {
            a0 += v0 * g[(size_t)c0 * C + lane];
            a1 += v1 * g[(size_t)c1 * C + lane];
            a2 += v2 * g[(size_t)c2 * C + lane];
            a3 += v3 * g[(size_t)c3 * C + lane];
        }
    }
    if (w == 0) {  // tail (< 4 entries)
        for (int e = nz & ~3; e < nz; ++e)
            if (act) a0 += rv[e] * g[(size_t)rc[e] * C + lane];
    }
    __shared__ float red[4][64];
    red[w][lane] = (a0 + a1) + (a2 + a3);
    __syncthreads();
    if (w == 0) {
        float o = 0.f;
        if (act) {
            float a = (red[0][lane] + red[1][lane]) + (red[2][lane] + red[3][lane])
                    + 2.0f * g[(size_t)row * C + lane];
            o = dinv[row] * a + bias[lane];
            if (do_tanh) o = tanhf(o);
            out[(size_t)row * C + lane] = o;
        }
        if (p) {  // fused score = tanh((row . p) * rsqrt(p.p)); C==64 here
            float pv = p[lane];
            float d = o * pv, pp = pv * pv;
            for (int off = 32; off; off >>= 1) {
                d  += __shfl_down(d, off, 64);
                pp += __shfl_down(pp, off, 64);
            }
            if (lane == 0) score[row] = tanhf(d * rsqrtf(pp));
        }
    }
}

// exact jax.lax.top_k order (value desc, index asc), rank-count.
// Block per candidate i; also initializes selpos[i] = -1 (grid covers all n).
__global__ void k_topk(const float* __restrict__ score, int* __restrict__ perm, int n, int k,
                       int* __restrict__ selpos) {
    int i = blockIdx.x;
    if (threadIdx.x == 0 && selpos) selpos[i] = -1;
    float si = score[i];
    int r = 0;
    for (int j = threadIdx.x; j < n; j += blockDim.x) {
        float sj = score[j];
        r += (sj > si) || (sj == si && j < i);
    }
    int lane = threadIdx.x & 63, wid = threadIdx.x >> 6;
    for (int off = 32; off; off >>= 1) r += __shfl_down(r, off, 64);
    __shared__ int red[4];
    if (lane == 0) red[wid] = r;
    __syncthreads();
    if (threadIdx.x == 0) {
        int rank = red[0] + red[1] + red[2] + red[3];
        if (rank < k) perm[rank] = i;
    }
}

// hp[i,:] = h[perm[i],:] * score[perm[i]]; also selpos[perm[i]] = i. block=64, grid=k
__global__ void k_pool(const float* __restrict__ h, const float* __restrict__ score,
                       const int* __restrict__ perm, float* __restrict__ hp,
                       int* __restrict__ selpos) {
    int i = blockIdx.x;
    int c = threadIdx.x;
    int pi = perm[i];
    hp[(size_t)i * HIDC + c] = h[(size_t)pi * HIDC + c] * score[pi];
    if (c == 0) selpos[pi] = i;
}

// Bcol[row][j] = B[row, perm[j]] (B = T with diag forced 1); Bcol pre-zeroed.
__global__ void k_bcol_scatter(const int* __restrict__ cols, const float* __restrict__ vals,
                               const int* __restrict__ cnt, int CAP,
                               const int* __restrict__ selpos, float* __restrict__ Bcol, int ldb) {
    int row = blockIdx.x;
    int nz = cnt[row];
    for (int e = threadIdx.x; e < nz; e += blockDim.x) {
        int c = cols[(size_t)row * CAP + e];
        if (c == row) continue;                 // diag handled below
        int j = selpos[c];
        if (j >= 0) Bcol[(size_t)row * ldb + j] = vals[(size_t)row * CAP + e];
    }
    if (threadIdx.x == 0) {
        int j = selpos[row];
        if (j >= 0) Bcol[(size_t)row * ldb + j] = 1.0f;  // B diag = 1
    }
}

// Tdst[i][j] = sum_k B[perm[i],k] * Bcol[k][j], diag(Tdst)=0.
// grid (rows, j-chunks); thread owns one float4 of j; CSR row in LDS; 4-way e-ILP.
__global__ void k_aug_csr(const int* __restrict__ perm,
                          const int* __restrict__ cols, const float* __restrict__ vals,
                          const int* __restrict__ cnt, int CAP,
                          const float* __restrict__ Bcol, int ldb,
                          float* __restrict__ Tdst, int ldt, int kk) {
    __shared__ int   scol[CAPMAX];
    __shared__ float sval[CAPMAX];
    int i = blockIdx.x;
    int pi = perm[i];
    int nz = cnt[pi];
    for (int e = threadIdx.x; e < nz; e += blockDim.x) {
        int c = cols[(size_t)pi * CAP + e];
        scol[e] = c;
        sval[e] = (c == pi) ? 0.0f : vals[(size_t)pi * CAP + e];  // diag via explicit Bcol[pi] term
    }
    __syncthreads();
    int j = (blockIdx.y * blockDim.x + threadIdx.x) * 4;
    if (j >= kk) return;
    int j4 = j >> 2;
    float4 a = ((const float4*)(Bcol + (size_t)pi * ldb))[j4];   // 1 * B[pi, perm[j..j+3]]
    int e = 0;
    for (; e + 4 <= nz; e += 4) {
        float v0 = sval[e], v1 = sval[e + 1], v2 = sval[e + 2], v3 = sval[e + 3];
        float4 b0 = ((const float4*)(Bcol + (size_t)scol[e]     * ldb))[j4];
        float4 b1 = ((const float4*)(Bcol + (size_t)scol[e + 1] * ldb))[j4];
        float4 b2 = ((const float4*)(Bcol + (size_t)scol[e + 2] * ldb))[j4];
        float4 b3 = ((const float4*)(Bcol + (size_t)scol[e + 3] * ldb))[j4];
        a.x += v0 * b0.x + v1 * b1.x + v2 * b2.x + v3 * b3.x;
        a.y += v0 * b0.y + v1 * b1.y + v2 * b2.y + v3 * b3.y;
        a.z += v0 * b0.z + v1 * b1.z + v2 * b2.z + v3 * b3.z;
        a.w += v0 * b0.w + v1 * b1.w + v2 * b2.w + v3 * b3.w;
    }
    for (; e < nz; ++e) {
        float v = sval[e];
        float4 b = ((const float4*)(Bcol + (size_t)scol[e] * ldb))[j4];
        a.x += v * b.x; a.y += v * b.y; a.z += v * b.z; a.w += v * b.w;
    }
    if (i >= j && i < j + 4) ((float*)&a)[i - j] = 0.0f;         // zero output diag
    *(float4*)(Tdst + (size_t)i * ldt + j) = a;
}

// ---------------- launch ----------------

extern "C" void kernel_launch(void* const* d_in, const int* in_sizes, int n_in,
                              void* d_out, int out_size, void* d_ws, size_t ws_size,
                              hipStream_t stream) {
    const float* x   = (const float*)d_in[0];
    const int*   ei  = (const int*)d_in[1];
    const float* W0  = (const float*)d_in[2];
    const float* b0  = (const float*)d_in[3];
    const float* W1  = (const float*)d_in[4];
    const float* b1  = (const float*)d_in[5];
    const float* W2  = (const float*)d_in[6];
    const float* b2  = (const float*)d_in[7];
    const float* p1  = (const float*)d_in[8];
    const float* p2  = (const float*)d_in[9];
    const float* Wu0 = (const float*)d_in[10];
    const float* bu0 = (const float*)d_in[11];
    const float* Wu1 = (const float*)d_in[12];
    const float* bu1 = (const float*)d_in[13];
    float* out = (float*)d_out;

    // ---- workspace layout (float units; every chunk a multiple of 4 floats) ----
    float* fw = (float*)d_ws;
    size_t off = 0;
    float* T0   = fw + off; off += (size_t)NN * NN;        // 9,000,000
    float* T1   = fw + off; off += (size_t)KK1 * KK1;      // 2,250,000
    float* T2   = fw + off; off += (size_t)KK2 * KK2P;     //   564,000 (ld = 752)
    float* REG  = fw + off; off += (size_t)NN * KK1;       // 4,500,000 (Bcol | {csr1, Bcol2})
    int*   cols0 = (int*)(fw + off); off += (size_t)NN * CAP0;
    float* vals0 = fw + off;         off += (size_t)NN * CAP0;
    int*   cols2 = (int*)(fw + off); off += (size_t)KK2 * CAP2;
    float* vals2 = fw + off;         off += (size_t)KK2 * CAP2;
    int*   cnt0  = (int*)(fw + off); off += NN;
    int*   cnt1  = (int*)(fw + off); off += KK1;
    int*   cnt2  = (int*)(fw + off); off += KK2P;
    float* g     = fw + off; off += (size_t)NN * HIDC;
    float* res0  = fw + off; off += (size_t)NN * HIDC;
    float* res1  = fw + off; off += (size_t)KK1 * HIDC;
    float* hp    = fw + off; off += (size_t)KK1 * HIDC;
    float* hp2   = fw + off; off += (size_t)KK2 * HIDC;
    float* x2    = fw + off; off += (size_t)KK2 * HIDC;
    float* xu    = fw + off; off += (size_t)KK1 * HIDC;
    float* sc1   = fw + off; off += NN;
    float* sc2   = fw + off; off += KK1;
    float* dinv0 = fw + off; off += NN;
    float* dinv1 = fw + off; off += KK1;
    float* dinv2 = fw + off; off += KK2P;
    int* perm1   = (int*)(fw + off); off += KK1;
    int* perm2   = (int*)(fw + off); off += KK2P;
    int* selpos1 = (int*)(fw + off); off += NN;
    int* selpos2 = (int*)(fw + off); off += KK1;
    if (ws_size < off * sizeof(float)) return;

    // region aliases (lifetimes disjoint, stream-ordered)
    float* Bcol  = REG;                                    // NN x KK1      (pool-1 phase)
    int*   cols1 = (int*)REG;                              // KK1 x CAP1
    float* vals1 = REG + (size_t)KK1 * CAP1;               // KK1 x CAP1
    float* Bcol2 = REG + 2 * (size_t)KK1 * CAP1;           // KK1 x KK2P

    dim3 b64(64), b256(256);

    // ---- A0 (transposed) dense, then CSR0 (+dinv0)
    hipMemsetAsync(T0, 0, (size_t)NN * NN * sizeof(float), stream);
    k_scatter_edges<<<dim3((EE + 255) / 256), b256, 0, stream>>>(ei, T0);
    k_csr_build<<<dim3((NN + 3) / 4), b256, 0, stream>>>(T0, NN, NN, NN, cols0, vals0, cnt0, CAP0, dinv0);

    // ---- GCN0 -> res0 (+score sc1)
    k_xw_scale<<<dim3(NN), b64, 0, stream>>>(x, nullptr, nullptr, W0, dinv0, g, NN, 16, 64);
    k_gcn_agg_csr<<<dim3(NN), b256, 0, stream>>>(cols0, vals0, cnt0, CAP0, g, dinv0, b0, res0, NN, 64, 1, p1, sc1);

    // ---- pool 1
    k_topk<<<dim3(NN), b256, 0, stream>>>(sc1, perm1, NN, KK1, selpos1);
    k_pool<<<dim3(KK1), b64, 0, stream>>>(res0, sc1, perm1, hp, selpos1);
    hipMemsetAsync(Bcol, 0, (size_t)NN * KK1 * sizeof(float), stream);
    k_bcol_scatter<<<dim3(NN), b64, 0, stream>>>(cols0, vals0, cnt0, CAP0, selpos1, Bcol, KK1);
    k_aug_csr<<<dim3(KK1, 2), b256, 0, stream>>>(perm1, cols0, vals0, cnt0, CAP0, Bcol, KK1, T1, KK1, KK1);

    // ---- CSR1 (+dinv1) (aliases onto Bcol region — Bcol dead)
    k_csr_build<<<dim3((KK1 + 3) / 4), b256, 0, stream>>>(T1, KK1, KK1, KK1, cols1, vals1, cnt1, CAP1, dinv1);

    // ---- GCN1 -> res1 (+score sc2)
    k_xw_scale<<<dim3(KK1), b64, 0, stream>>>(hp, nullptr, nullptr, W1, dinv1, g, KK1, 64, 64);
    k_gcn_agg_csr<<<dim3(KK1), b256, 0, stream>>>(cols1, vals1, cnt1, CAP1, g, dinv1, b1, res1, KK1, 64, 1, p2, sc2);

    // ---- pool 2
    k_topk<<<dim3(KK1), b256, 0, stream>>>(sc2, perm2, KK1, KK2, selpos2);
    k_pool<<<dim3(KK2), b64, 0, stream>>>(res1, sc2, perm2, hp2, selpos2);
    hipMemsetAsync(Bcol2, 0, (size_t)KK1 * KK2P * sizeof(float), stream);
    k_bcol_scatter<<<dim3(KK1), b64, 0, stream>>>(cols1, vals1, cnt1, CAP1, selpos2, Bcol2, KK2P);
    k_aug_csr<<<dim3(KK2, 1), b256, 0, stream>>>(perm2, cols1, vals1, cnt1, CAP1, Bcol2, KK2P, T2, KK2P, KK2);

    // ---- CSR2 (+dinv2) (CAP2=768 >= 750: lossless)
    k_csr_build<<<dim3((KK2 + 3) / 4), b256, 0, stream>>>(T2, KK2P, KK2, KK2, cols2, vals2, cnt2, CAP2, dinv2);

    // ---- GCN2 -> x2
    k_xw_scale<<<dim3(KK2), b64, 0, stream>>>(hp2, nullptr, nullptr, W2, dinv2, g, KK2, 64, 64);
    k_gcn_agg_csr<<<dim3(KK2), b256, 0, stream>>>(cols2, vals2, cnt2, CAP2, g, dinv2, b2, x2, KK2, 64, 1, nullptr, nullptr);

    // ---- up to level 1: h = res1 + up(x2 via selpos2); GCN(Wu0) -> xu
    k_xw_scale<<<dim3(KK1), b64, 0, stream>>>(res1, x2, selpos2, Wu0, dinv1, g, KK1, 64, 64);
    k_gcn_agg_csr<<<dim3(KK1), b256, 0, stream>>>(cols1, vals1, cnt1, CAP1, g, dinv1, bu0, xu, KK1, 64, 1, nullptr, nullptr);

    // ---- up to level 0: h = res0 + up(xu via selpos1); GCN(Wu1) -> out (no tanh)
    k_xw_scale<<<dim3(NN), b64, 0, stream>>>(res0, xu, selpos1, Wu1, dinv0, g, NN, 64, 16);
    k_gcn_agg_csr<<<dim3(NN), b256, 0, stream>>>(cols0, vals0, cnt0, CAP0, g, dinv0, bu1, out, NN, 16, 0, nullptr, nullptr);
}

// Round 7
// 230.494 us; speedup vs baseline: 4.9743x; 1.0923x over previous
//
#include <hip/hip_runtime.h>

#define NN   3000
#define EE   48000
#define KK1  1500
#define KK2  750
#define KK2P 752      // padded row stride for Bcol2 (float4 alignment)
#define HIDC 64
#define SLOT 64       // max raw in-degree slots (mean 16, Poisson tail safe)

#define CAP0 64
#define CAP1 768
#define CAP2 768
#define CAPMAX 768

// ---------------- kernels ----------------

// per-edge slot scatter: slots[t][idx] = s, idx = atomic count
__global__ void k_edge_slots(const int* __restrict__ ei, int* __restrict__ cntraw,
                             int* __restrict__ slots) {
    int e = blockIdx.x * blockDim.x + threadIdx.x;
    if (e >= EE) return;
    int s = ei[e];        // source
    int t = ei[EE + e];   // target
    int idx = atomicAdd(&cntraw[t], 1);
    if (idx < SLOT) slots[t * SLOT + idx] = s;
}

// wave per row: sort+dedup slot entries -> CSR0 (col asc, multiplicity vals) + dinv0.
// Deterministic: output depends only on the multiset of sources per target.
__global__ void k_csr0_sort(const int* __restrict__ cntraw, const int* __restrict__ slots,
                            int* __restrict__ cols, float* __restrict__ vals,
                            int* __restrict__ cnt, float* __restrict__ dinv) {
    int row = blockIdx.x * (blockDim.x >> 6) + (threadIdx.x >> 6);   // 4 rows/block, 3000%4==0
    int lane = threadIdx.x & 63;
    int raw = cntraw[row];
    int nz = raw < SLOT ? raw : SLOT;
    int my = (lane < nz) ? slots[row * SLOT + lane] : 0x7FFFFFFF;
    int dup_before = 0, equal_total = 0;
    for (int f = 0; f < 64; ++f) {
        int cf = __shfl(my, f, 64);
        if (cf == my) { equal_total++; if (f < lane) dup_before++; }
    }
    bool leader = (lane < nz) && (dup_before == 0);
    unsigned long long lm = __ballot(leader);
    int dl = 0;
    unsigned long long m = lm;
    while (m) {                      // iterate leader lanes (wave-uniform sequence)
        int f = __builtin_ctzll(m); m &= m - 1;
        int cf = __shfl(my, f, 64);
        dl += (cf < my);
    }
    if (leader) {
        cols[(size_t)row * CAP0 + dl] = my;
        vals[(size_t)row * CAP0 + dl] = (float)equal_total;   // duplicate edges sum
    }
    if (lane == 0) {
        cnt[row] = __popcll(lm);
        dinv[row] = rsqrtf((float)raw + 2.0f);                // in-degree + self-loop wt 2
    }
}

// g[i,:] = dinv[i] * ((h[i,:] + up[selpos[i],:]) @ W); block=64, grid=n
__global__ void k_xw_scale(const float* __restrict__ h, const float* __restrict__ up,
                           const int* __restrict__ selpos,
                           const float* __restrict__ W, const float* __restrict__ dinv,
                           float* __restrict__ g, int n, int IC, int OC) {
    int row = blockIdx.x;
    int c = threadIdx.x;
    __shared__ float hr[64];
    if (c < IC) {
        float v = h[(size_t)row * IC + c];
        if (selpos) {
            int sp = selpos[row];
            if (sp >= 0) v += up[(size_t)sp * IC + c];
        }
        hr[c] = v;
    }
    __syncthreads();
    if (c >= OC) return;
    float acc = 0.0f;
    for (int k = 0; k < IC; ++k) acc += hr[k] * W[k * OC + c];
    g[(size_t)row * OC + c] = dinv[row] * acc;
}

// out[t,:] = act( dinv[t] * ( sum_e val_e * g[col_e,:] + 2*g[t,:] ) + b )
// Block per row, 4 waves split nonzeros (16-entry rounds, 4-ILP), LDS reduce;
// wave 0 finishes + optional fused TopK score (C==64).
__global__ void k_gcn_agg_csr(const int* __restrict__ cols, const float* __restrict__ vals,
                              const int* __restrict__ cnt, int CAP,
                              const float* __restrict__ g, const float* __restrict__ dinv,
                              const float* __restrict__ bias, float* __restrict__ out,
                              int n, int C, int do_tanh,
                              const float* __restrict__ p, float* __restrict__ score) {
    int row = blockIdx.x;
    int w = threadIdx.x >> 6;
    int lane = threadIdx.x & 63;
    int nz = cnt[row];
    const int*   rc = cols + (size_t)row * CAP;
    const float* rv = vals + (size_t)row * CAP;
    bool act = lane < C;
    float a0 = 0.f, a1 = 0.f, a2 = 0.f, a3 = 0.f;
    for (int e = 4 * w; e + 4 <= nz; e += 16) {
        int   c0 = rc[e], c1 = rc[e + 1], c2 = rc[e + 2], c3 = rc[e + 3];
        float v0 = rv[e], v1 = rv[e + 1], v2 = rv[e + 2], v3 = rv[e + 3];
        if (act) {
            a0 += v0 * g[(size_t)c0 * C + lane];
            a1 += v1 * g[(size_t)c1 * C + lane];
            a2 += v2 * g[(size_t)c2 * C + lane];
            a3 += v3 * g[(size_t)c3 * C + lane];
        }
    }
    if (w == 0) {  // tail (< 4 entries)
        for (int e = nz & ~3; e < nz; ++e)
            if (act) a0 += rv[e] * g[(size_t)rc[e] * C + lane];
    }
    __shared__ float red[4][64];
    red[w][lane] = (a0 + a1) + (a2 + a3);
    __syncthreads();
    if (w == 0) {
        float o = 0.f;
        if (act) {
            float a = (red[0][lane] + red[1][lane]) + (red[2][lane] + red[3][lane])
                    + 2.0f * g[(size_t)row * C + lane];
            o = dinv[row] * a + bias[lane];
            if (do_tanh) o = tanhf(o);
            out[(size_t)row * C + lane] = o;
        }
        if (p) {  // fused score = tanh((row . p) * rsqrt(p.p)); C==64 here
            float pv = p[lane];
            float d = o * pv, pp = pv * pv;
            for (int off = 32; off; off >>= 1) {
                d  += __shfl_down(d, off, 64);
                pp += __shfl_down(pp, off, 64);
            }
            if (lane == 0) score[row] = tanhf(d * rsqrtf(pp));
        }
    }
}

// exact jax.lax.top_k order (value desc, index asc), rank-count.
// Block per candidate i; also initializes selpos[i] = -1 (grid covers all n).
__global__ void k_topk(const float* __restrict__ score, int* __restrict__ perm, int n, int k,
                       int* __restrict__ selpos) {
    int i = blockIdx.x;
    if (threadIdx.x == 0 && selpos) selpos[i] = -1;
    float si = score[i];
    int r = 0;
    for (int j = threadIdx.x; j < n; j += blockDim.x) {
        float sj = score[j];
        r += (sj > si) || (sj == si && j < i);
    }
    int lane = threadIdx.x & 63, wid = threadIdx.x >> 6;
    for (int off = 32; off; off >>= 1) r += __shfl_down(r, off, 64);
    __shared__ int red[4];
    if (lane == 0) red[wid] = r;
    __syncthreads();
    if (threadIdx.x == 0) {
        int rank = red[0] + red[1] + red[2] + red[3];
        if (rank < k) perm[rank] = i;
    }
}

// hp[i,:] = h[perm[i],:] * score[perm[i]]; also selpos[perm[i]] = i. block=64, grid=k
__global__ void k_pool(const float* __restrict__ h, const float* __restrict__ score,
                       const int* __restrict__ perm, float* __restrict__ hp,
                       int* __restrict__ selpos) {
    int i = blockIdx.x;
    int c = threadIdx.x;
    int pi = perm[i];
    hp[(size_t)i * HIDC + c] = h[(size_t)pi * HIDC + c] * score[pi];
    if (c == 0) selpos[pi] = i;
}

// Bcol[row][j] = B[row, perm[j]] (B = T with diag forced 1); Bcol pre-zeroed.
__global__ void k_bcol_scatter(const int* __restrict__ cols, const float* __restrict__ vals,
                               const int* __restrict__ cnt, int CAP,
                               const int* __restrict__ selpos, float* __restrict__ Bcol, int ldb) {
    int row = blockIdx.x;
    int nz = cnt[row];
    for (int e = threadIdx.x; e < nz; e += blockDim.x) {
        int c = cols[(size_t)row * CAP + e];
        if (c == row) continue;                 // diag handled below
        int j = selpos[c];
        if (j >= 0) Bcol[(size_t)row * ldb + j] = vals[(size_t)row * CAP + e];
    }
    if (threadIdx.x == 0) {
        int j = selpos[row];
        if (j >= 0) Bcol[(size_t)row * ldb + j] = 1.0f;  // B diag = 1
    }
}

// Fused augment+CSR: row i of Tdst = B[perm[i],:] @ Bcol (diag of B = 1 via explicit
// Bcol[pi] term; diag of Tdst zeroed), computed into LDS; rowsum -> dinv;
// wave 0 ballot-compacts LDS row straight to CSR. Dense Tdst never materialized.
__global__ void k_aug_fused(const int* __restrict__ perm,
                            const int* __restrict__ colsS, const float* __restrict__ valsS,
                            const int* __restrict__ cntS, int CAPS,
                            const float* __restrict__ Bcol, int ldb, int kk,
                            int* __restrict__ colsD, float* __restrict__ valsD,
                            int* __restrict__ cntD, float* __restrict__ dinvD, int CAPD) {
    __shared__ int   scol[CAPMAX];
    __shared__ float sval[CAPMAX];
    __shared__ float srow[1504];
    __shared__ float ssum[4];
    int i = blockIdx.x;
    int pi = perm[i];
    int nz = cntS[pi];
    for (int e = threadIdx.x; e < nz; e += blockDim.x) {
        int c = colsS[(size_t)pi * CAPS + e];
        scol[e] = c;
        sval[e] = (c == pi) ? 0.0f : valsS[(size_t)pi * CAPS + e];
    }
    __syncthreads();
    float psum = 0.0f;
    for (int j0 = threadIdx.x * 4; j0 < kk; j0 += blockDim.x * 4) {
        int j4 = j0 >> 2;
        float4 a = ((const float4*)(Bcol + (size_t)pi * ldb))[j4];   // diag term
        int e = 0;
        for (; e + 4 <= nz; e += 4) {
            float v0 = sval[e], v1 = sval[e + 1], v2 = sval[e + 2], v3 = sval[e + 3];
            float4 b0 = ((const float4*)(Bcol + (size_t)scol[e]     * ldb))[j4];
            float4 b1 = ((const float4*)(Bcol + (size_t)scol[e + 1] * ldb))[j4];
            float4 b2 = ((const float4*)(Bcol + (size_t)scol[e + 2] * ldb))[j4];
            float4 b3 = ((const float4*)(Bcol + (size_t)scol[e + 3] * ldb))[j4];
            a.x += v0 * b0.x + v1 * b1.x + v2 * b2.x + v3 * b3.x;
            a.y += v0 * b0.y + v1 * b1.y + v2 * b2.y + v3 * b3.y;
            a.z += v0 * b0.z + v1 * b1.z + v2 * b2.z + v3 * b3.z;
            a.w += v0 * b0.w + v1 * b1.w + v2 * b2.w + v3 * b3.w;
        }
        for (; e < nz; ++e) {
            float v = sval[e];
            float4 b = ((const float4*)(Bcol + (size_t)scol[e] * ldb))[j4];
            a.x += v * b.x; a.y += v * b.y; a.z += v * b.z; a.w += v * b.w;
        }
        if (i >= j0 && i < j0 + 4) ((float*)&a)[i - j0] = 0.0f;      // zero output diag
        *(float4*)(srow + j0) = a;
        psum += (a.x + a.y) + (a.z + a.w);
    }
    int lane = threadIdx.x & 63, w = threadIdx.x >> 6;
    for (int off = 32; off; off >>= 1) psum += __shfl_down(psum, off, 64);
    if (lane == 0) ssum[w] = psum;
    __syncthreads();
    if (w == 0) {
        if (lane == 0)
            dinvD[i] = rsqrtf((ssum[0] + ssum[1]) + (ssum[2] + ssum[3]) + 2.0f);
        int base = 0;
        for (int c0 = 0; c0 < kk; c0 += 64) {
            int c = c0 + lane;
            float v = (c < kk) ? srow[c] : 0.0f;
            unsigned long long mb = __ballot(v != 0.0f);
            if (v != 0.0f) {
                int idx = base + __popcll(mb & ((1ull << lane) - 1ull));
                if (idx < CAPD) {
                    colsD[(size_t)i * CAPD + idx] = c;
                    valsD[(size_t)i * CAPD + idx] = v;
                }
            }
            base += __popcll(mb);
        }
        if (lane == 0) cntD[i] = base < CAPD ? base : CAPD;
    }
}

// ---------------- launch ----------------

extern "C" void kernel_launch(void* const* d_in, const int* in_sizes, int n_in,
                              void* d_out, int out_size, void* d_ws, size_t ws_size,
                              hipStream_t stream) {
    const float* x   = (const float*)d_in[0];
    const int*   ei  = (const int*)d_in[1];
    const float* W0  = (const float*)d_in[2];
    const float* b0  = (const float*)d_in[3];
    const float* W1  = (const float*)d_in[4];
    const float* b1  = (const float*)d_in[5];
    const float* W2  = (const float*)d_in[6];
    const float* b2  = (const float*)d_in[7];
    const float* p1  = (const float*)d_in[8];
    const float* p2  = (const float*)d_in[9];
    const float* Wu0 = (const float*)d_in[10];
    const float* bu0 = (const float*)d_in[11];
    const float* Wu1 = (const float*)d_in[12];
    const float* bu1 = (const float*)d_in[13];
    float* out = (float*)d_out;

    // ---- workspace layout (float units; chunks multiple of 4) ----
    float* fw = (float*)d_ws;
    size_t off = 0;
    int*   slots = (int*)(fw + off); off += (size_t)NN * SLOT;
    int*   cntraw = (int*)(fw + off); off += NN;
    int*   cols0 = (int*)(fw + off); off += (size_t)NN * CAP0;
    float* vals0 = fw + off;         off += (size_t)NN * CAP0;
    int*   cols1 = (int*)(fw + off); off += (size_t)KK1 * CAP1;
    float* vals1 = fw + off;         off += (size_t)KK1 * CAP1;
    int*   cols2 = (int*)(fw + off); off += (size_t)KK2 * CAP2;
    float* vals2 = fw + off;         off += (size_t)KK2 * CAP2;
    float* Bcol  = fw + off; off += (size_t)NN * KK1;
    float* Bcol2 = fw + off; off += (size_t)KK1 * KK2P;
    int*   cnt0  = (int*)(fw + off); off += NN;
    int*   cnt1  = (int*)(fw + off); off += KK1;
    int*   cnt2  = (int*)(fw + off); off += KK2P;
    float* g     = fw + off; off += (size_t)NN * HIDC;
    float* res0  = fw + off; off += (size_t)NN * HIDC;
    float* res1  = fw + off; off += (size_t)KK1 * HIDC;
    float* hp    = fw + off; off += (size_t)KK1 * HIDC;
    float* hp2   = fw + off; off += (size_t)KK2 * HIDC;
    float* x2    = fw + off; off += (size_t)KK2 * HIDC;
    float* xu    = fw + off; off += (size_t)KK1 * HIDC;
    float* sc1   = fw + off; off += NN;
    float* sc2   = fw + off; off += KK1;
    float* dinv0 = fw + off; off += NN;
    float* dinv1 = fw + off; off += KK1;
    float* dinv2 = fw + off; off += KK2P;
    int* perm1   = (int*)(fw + off); off += KK1;
    int* perm2   = (int*)(fw + off); off += KK2P;
    int* selpos1 = (int*)(fw + off); off += NN;
    int* selpos2 = (int*)(fw + off); off += KK1;
    if (ws_size < off * sizeof(float)) return;

    dim3 b64(64), b256(256);

    // ---- CSR0 + dinv0 directly from edge list (no dense T0)
    hipMemsetAsync(cntraw, 0, NN * sizeof(int), stream);
    k_edge_slots<<<dim3((EE + 255) / 256), b256, 0, stream>>>(ei, cntraw, slots);
    k_csr0_sort<<<dim3(NN / 4), b256, 0, stream>>>(cntraw, slots, cols0, vals0, cnt0, dinv0);

    // ---- GCN0 -> res0 (+score sc1)
    k_xw_scale<<<dim3(NN), b64, 0, stream>>>(x, nullptr, nullptr, W0, dinv0, g, NN, 16, 64);
    k_gcn_agg_csr<<<dim3(NN), b256, 0, stream>>>(cols0, vals0, cnt0, CAP0, g, dinv0, b0, res0, NN, 64, 1, p1, sc1);

    // ---- pool 1
    k_topk<<<dim3(NN), b256, 0, stream>>>(sc1, perm1, NN, KK1, selpos1);
    k_pool<<<dim3(KK1), b64, 0, stream>>>(res0, sc1, perm1, hp, selpos1);
    hipMemsetAsync(Bcol, 0, (size_t)NN * KK1 * sizeof(float), stream);
    k_bcol_scatter<<<dim3(NN), b64, 0, stream>>>(cols0, vals0, cnt0, CAP0, selpos1, Bcol, KK1);
    k_aug_fused<<<dim3(KK1), b256, 0, stream>>>(perm1, cols0, vals0, cnt0, CAP0,
                                                Bcol, KK1, KK1, cols1, vals1, cnt1, dinv1, CAP1);

    // ---- GCN1 -> res1 (+score sc2)
    k_xw_scale<<<dim3(KK1), b64, 0, stream>>>(hp, nullptr, nullptr, W1, dinv1, g, KK1, 64, 64);
    k_gcn_agg_csr<<<dim3(KK1), b256, 0, stream>>>(cols1, vals1, cnt1, CAP1, g, dinv1, b1, res1, KK1, 64, 1, p2, sc2);

    // ---- pool 2
    k_topk<<<dim3(KK1), b256, 0, stream>>>(sc2, perm2, KK1, KK2, selpos2);
    k_pool<<<dim3(KK2), b64, 0, stream>>>(res1, sc2, perm2, hp2, selpos2);
    hipMemsetAsync(Bcol2, 0, (size_t)KK1 * KK2P * sizeof(float), stream);
    k_bcol_scatter<<<dim3(KK1), b64, 0, stream>>>(cols1, vals1, cnt1, CAP1, selpos2, Bcol2, KK2P);
    k_aug_fused<<<dim3(KK2), b256, 0, stream>>>(perm2, cols1, vals1, cnt1, CAP1,
                                                Bcol2, KK2P, KK2, cols2, vals2, cnt2, dinv2, CAP2);

    // ---- GCN2 -> x2
    k_xw_scale<<<dim3(KK2), b64, 0, stream>>>(hp2, nullptr, nullptr, W2, dinv2, g, KK2, 64, 64);
    k_gcn_agg_csr<<<dim3(KK2), b256, 0, stream>>>(cols2, vals2, cnt2, CAP2, g, dinv2, b2, x2, KK2, 64, 1, nullptr, nullptr);

    // ---- up to level 1: h = res1 + up(x2 via selpos2); GCN(Wu0) -> xu
    k_xw_scale<<<dim3(KK1), b64, 0, stream>>>(res1, x2, selpos2, Wu0, dinv1, g, KK1, 64, 64);
    k_gcn_agg_csr<<<dim3(KK1), b256, 0, stream>>>(cols1, vals1, cnt1, CAP1, g, dinv1, bu0, xu, KK1, 64, 1, nullptr, nullptr);

    // ---- up to level 0: h = res0 + up(xu via selpos1); GCN(Wu1) -> out (no tanh)
    k_xw_scale<<<dim3(NN), b64, 0, stream>>>(res0, xu, selpos1, Wu1, dinv0, g, NN, 64, 16);
    k_gcn_agg_csr<<<dim3(NN), b256, 0, stream>>>(cols0, vals0, cnt0, CAP0, g, dinv0, bu1, out, NN, 16, 0, nullptr, nullptr);
}

// Round 9
// 188.500 us; speedup vs baseline: 6.0825x; 1.2228x over previous
//
#include <hip/hip_runtime.h>

#define NN   3000
#define EE   48000
#define KK1  1500
#define KK2  750
#define HIDC 64
#define SLOT 64       // max raw in-degree slots (mean 16; Poisson tail safe)

#define CAP0  64      // CSR0 row capacity
#define CAP1  768     // CSR1 row capacity
#define CAP2  768     // CSR2 row capacity (>=750: lossless)
#define CAPB0 64      // filtered-CSR capacity, level 0 -> 1
#define CAPB1 768     // filtered-CSR capacity, level 1 -> 2

// ---------------- kernels ----------------

// per-edge slot scatter: slots[t][idx] = s, idx = atomic count
__global__ void k_edge_slots(const int* __restrict__ ei, int* __restrict__ cntraw,
                             int* __restrict__ slots) {
    int e = blockIdx.x * blockDim.x + threadIdx.x;
    if (e >= EE) return;
    int s = ei[e];        // source
    int t = ei[EE + e];   // target
    int idx = atomicAdd(&cntraw[t], 1);
    if (idx < SLOT) slots[t * SLOT + idx] = s;
}

// wave per row: sort+dedup slot entries -> CSR0 (col asc, multiplicity vals) + dinv0.
// Deterministic: output depends only on the multiset of sources per target.
__global__ void k_csr0_sort(const int* __restrict__ cntraw, const int* __restrict__ slots,
                            int* __restrict__ cols, float* __restrict__ vals,
                            int* __restrict__ cnt, float* __restrict__ dinv) {
    int row = blockIdx.x * (blockDim.x >> 6) + (threadIdx.x >> 6);   // 4 rows/block
    int lane = threadIdx.x & 63;
    int raw = cntraw[row];
    int nz = raw < SLOT ? raw : SLOT;
    int my = (lane < nz) ? slots[row * SLOT + lane] : 0x7FFFFFFF;
    int dup_before = 0, equal_total = 0;
    for (int f = 0; f < 64; ++f) {
        int cf = __shfl(my, f, 64);
        if (cf == my) { equal_total++; if (f < lane) dup_before++; }
    }
    bool leader = (lane < nz) && (dup_before == 0);
    unsigned long long lm = __ballot(leader);
    int dl = 0;
    unsigned long long m = lm;
    while (m) {                      // iterate leader lanes (wave-uniform sequence)
        int f = __builtin_ctzll(m); m &= m - 1;
        int cf = __shfl(my, f, 64);
        dl += (cf < my);
    }
    if (leader) {
        cols[(size_t)row * CAP0 + dl] = my;
        vals[(size_t)row * CAP0 + dl] = (float)equal_total;   // duplicate edges sum
    }
    if (lane == 0) {
        cnt[row] = __popcll(lm);
        dinv[row] = rsqrtf((float)raw + 2.0f);                // in-degree + self-loop wt 2
    }
}

// g[i,:] = dinv[i] * ((h[i,:] + up[selpos[i],:]) @ W); block=64, grid=n
__global__ void k_xw_scale(const float* __restrict__ h, const float* __restrict__ up,
                           const int* __restrict__ selpos,
                           const float* __restrict__ W, const float* __restrict__ dinv,
                           float* __restrict__ g, int n, int IC, int OC) {
    int row = blockIdx.x;
    int c = threadIdx.x;
    __shared__ float hr[64];
    if (c < IC) {
        float v = h[(size_t)row * IC + c];
        if (selpos) {
            int sp = selpos[row];
            if (sp >= 0) v += up[(size_t)sp * IC + c];
        }
        hr[c] = v;
    }
    __syncthreads();
    if (c >= OC) return;
    float acc = 0.0f;
    for (int k = 0; k < IC; ++k) acc += hr[k] * W[k * OC + c];
    g[(size_t)row * OC + c] = dinv[row] * acc;
}

// out[t,:] = act( dinv[t] * ( sum_e val_e * g[col_e,:] + 2*g[t,:] ) + b )
// Block per row, 4 waves split nonzeros (16-entry rounds, 4-ILP), LDS reduce;
// wave 0 finishes + optional fused TopK score (C==64).
__global__ void k_gcn_agg_csr(const int* __restrict__ cols, const float* __restrict__ vals,
                              const int* __restrict__ cnt, int CAP,
                              const float* __restrict__ g, const float* __restrict__ dinv,
                              const float* __restrict__ bias, float* __restrict__ out,
                              int n, int C, int do_tanh,
                              const float* __restrict__ p, float* __restrict__ score) {
    int row = blockIdx.x;
    int w = threadIdx.x >> 6;
    int lane = threadIdx.x & 63;
    int nz = cnt[row];
    const int*   rc = cols + (size_t)row * CAP;
    const float* rv = vals + (size_t)row * CAP;
    bool act = lane < C;
    float a0 = 0.f, a1 = 0.f, a2 = 0.f, a3 = 0.f;
    for (int e = 4 * w; e + 4 <= nz; e += 16) {
        int   c0 = rc[e], c1 = rc[e + 1], c2 = rc[e + 2], c3 = rc[e + 3];
        float v0 = rv[e], v1 = rv[e + 1], v2 = rv[e + 2], v3 = rv[e + 3];
        if (act) {
            a0 += v0 * g[(size_t)c0 * C + lane];
            a1 += v1 * g[(size_t)c1 * C + lane];
            a2 += v2 * g[(size_t)c2 * C + lane];
            a3 += v3 * g[(size_t)c3 * C + lane];
        }
    }
    if (w == 0) {  // tail (< 4 entries)
        for (int e = nz & ~3; e < nz; ++e)
            if (act) a0 += rv[e] * g[(size_t)rc[e] * C + lane];
    }
    __shared__ float red[4][64];
    red[w][lane] = (a0 + a1) + (a2 + a3);
    __syncthreads();
    if (w == 0) {
        float o = 0.f;
        if (act) {
            float a = (red[0][lane] + red[1][lane]) + (red[2][lane] + red[3][lane])
                    + 2.0f * g[(size_t)row * C + lane];
            o = dinv[row] * a + bias[lane];
            if (do_tanh) o = tanhf(o);
            out[(size_t)row * C + lane] = o;
        }
        if (p) {  // fused score = tanh((row . p) * rsqrt(p.p)); C==64 here
            float pv = p[lane];
            float d = o * pv, pp = pv * pv;
            for (int off = 32; off; off >>= 1) {
                d  += __shfl_down(d, off, 64);
                pp += __shfl_down(pp, off, 64);
            }
            if (lane == 0) score[row] = tanhf(d * rsqrtf(pp));
        }
    }
}

// exact jax.lax.top_k order (value desc, index asc), rank-count; fused pool:
// block per candidate i; selpos[i] = rank (or -1); if selected, writes
// hp[rank,:] = h[i,:] * score[i].
__global__ void k_topk(const float* __restrict__ score, const float* __restrict__ h,
                       int n, int k, int* __restrict__ perm, int* __restrict__ selpos,
                       float* __restrict__ hp) {
    int i = blockIdx.x;
    float si = score[i];
    int r = 0;
    for (int j = threadIdx.x; j < n; j += blockDim.x) {
        float sj = score[j];
        r += (sj > si) || (sj == si && j < i);
    }
    int lane = threadIdx.x & 63, wid = threadIdx.x >> 6;
    for (int off = 32; off; off >>= 1) r += __shfl_down(r, off, 64);
    __shared__ int red[4];
    __shared__ int srank;
    if (lane == 0) red[wid] = r;
    __syncthreads();
    if (threadIdx.x == 0) {
        int rank = red[0] + red[1] + red[2] + red[3];
        srank = rank;
        selpos[i] = (rank < k) ? rank : -1;
        if (rank < k) perm[rank] = i;
    }
    __syncthreads();
    int rank = srank;
    if (rank < k && threadIdx.x < HIDC)
        hp[(size_t)rank * HIDC + threadIdx.x] = h[(size_t)i * HIDC + threadIdx.x] * si;
}

// Filtered CSR of B (= T offdiag + I) restricted to selected columns, remapped
// to compact j indices: entries (selpos[c], val) for c in row (c!=row, selected),
// plus (selpos[row], 1.0). Wave per row (4/block). Col-ascending, deterministic.
__global__ void k_bcolcsr(const int* __restrict__ cols, const float* __restrict__ vals,
                          const int* __restrict__ cnt, int CAPS,
                          const int* __restrict__ selpos, int n,
                          int* __restrict__ bcC, float* __restrict__ bcV,
                          int* __restrict__ bcN, int CAPB) {
    int row = blockIdx.x * (blockDim.x >> 6) + (threadIdx.x >> 6);
    int lane = threadIdx.x & 63;
    if (row >= n) return;
    int nz = cnt[row];
    int base = 0;
    for (int e0 = 0; e0 < nz; e0 += 64) {
        int e = e0 + lane;
        int j = -1; float v = 0.0f;
        if (e < nz) {
            int c = cols[(size_t)row * CAPS + e];
            if (c != row) { j = selpos[c]; v = vals[(size_t)row * CAPS + e]; }
        }
        unsigned long long mb = __ballot(j >= 0);
        if (j >= 0) {
            int idx = base + __popcll(mb & ((1ull << lane) - 1ull));
            if (idx < CAPB) { bcC[(size_t)row * CAPB + idx] = j; bcV[(size_t)row * CAPB + idx] = v; }
        }
        base += __popcll(mb);
    }
    if (lane == 0) {
        int jd = selpos[row];
        if (jd >= 0 && base < CAPB) {
            bcC[(size_t)row * CAPB + base] = jd;
            bcV[(size_t)row * CAPB + base] = 1.0f;     // B diag = 1
            base++;
        }
        bcN[row] = base < CAPB ? base : CAPB;
    }
}

// Sparse x sparse augment: output row i of Tdst = B[perm[i],:] @ B[:,selected],
// accumulated into a dense LDS row via atomicAdd (exact integer values ->
// order-independent, deterministic). Diag zeroed; rowsum -> dinv; wave 0
// ballot-compacts to CSR. Dense panels never touched.
__global__ void k_aug_sparse(const int* __restrict__ perm,
                             const int* __restrict__ colsS, const float* __restrict__ valsS,
                             const int* __restrict__ cntS, int CAPS,
                             const int* __restrict__ bcC, const float* __restrict__ bcV,
                             const int* __restrict__ bcN, int CAPB, int kk,
                             int* __restrict__ colsD, float* __restrict__ valsD,
                             int* __restrict__ cntD, float* __restrict__ dinvD, int CAPD) {
    __shared__ float srow[1504];
    __shared__ float ssum[4];
    int i = blockIdx.x;
    int pi = perm[i];
    int nzS = cntS[pi];
    for (int t = threadIdx.x; t < 1504; t += blockDim.x) srow[t] = 0.0f;
    __syncthreads();
    int w = threadIdx.x >> 6, lane = threadIdx.x & 63;
    // ee in [0, nzS]; ee == nzS is the implicit diag entry (k=pi, val=1)
    for (int ee = w; ee <= nzS; ee += 4) {
        int k; float kv;
        if (ee == nzS) { k = pi; kv = 1.0f; }
        else {
            k = colsS[(size_t)pi * CAPS + ee];
            if (k == pi) continue;               // original diag replaced by implicit 1
            kv = valsS[(size_t)pi * CAPS + ee];
        }
        int bn = bcN[k];
        const int*   bc = bcC + (size_t)k * CAPB;
        const float* bv = bcV + (size_t)k * CAPB;
        for (int t = lane; t < bn; t += 64)
            atomicAdd(&srow[bc[t]], kv * bv[t]);
    }
    __syncthreads();
    if (threadIdx.x == 0) srow[i] = 0.0f;        // zero output diag
    __syncthreads();
    float psum = 0.0f;
    for (int t = threadIdx.x; t < kk; t += blockDim.x) psum += srow[t];
    for (int off = 32; off; off >>= 1) psum += __shfl_down(psum, off, 64);
    if (lane == 0) ssum[w] = psum;
    __syncthreads();
    if (w == 0) {
        if (lane == 0)
            dinvD[i] = rsqrtf((ssum[0] + ssum[1]) + (ssum[2] + ssum[3]) + 2.0f);
        int base = 0;
        for (int c0 = 0; c0 < kk; c0 += 64) {
            int c = c0 + lane;
            float v = (c < kk) ? srow[c] : 0.0f;
            unsigned long long mb = __ballot(v != 0.0f);
            if (v != 0.0f) {
                int idx = base + __popcll(mb & ((1ull << lane) - 1ull));
                if (idx < CAPD) {
                    colsD[(size_t)i * CAPD + idx] = c;
                    valsD[(size_t)i * CAPD + idx] = v;
                }
            }
            base += __popcll(mb);
        }
        if (lane == 0) cntD[i] = base < CAPD ? base : CAPD;
    }
}

// ---------------- launch ----------------

extern "C" void kernel_launch(void* const* d_in, const int* in_sizes, int n_in,
                              void* d_out, int out_size, void* d_ws, size_t ws_size,
                              hipStream_t stream) {
    const float* x   = (const float*)d_in[0];
    const int*   ei  = (const int*)d_in[1];
    const float* W0  = (const float*)d_in[2];
    const float* b0  = (const float*)d_in[3];
    const float* W1  = (const float*)d_in[4];
    const float* b1  = (const float*)d_in[5];
    const float* W2  = (const float*)d_in[6];
    const float* b2  = (const float*)d_in[7];
    const float* p1  = (const float*)d_in[8];
    const float* p2  = (const float*)d_in[9];
    const float* Wu0 = (const float*)d_in[10];
    const float* bu0 = (const float*)d_in[11];
    const float* Wu1 = (const float*)d_in[12];
    const float* bu1 = (const float*)d_in[13];
    float* out = (float*)d_out;

    // ---- workspace layout (float units) ----
    float* fw = (float*)d_ws;
    size_t off = 0;
    int*   slots  = (int*)(fw + off); off += (size_t)NN * SLOT;
    int*   cntraw = (int*)(fw + off); off += NN;
    int*   cols0  = (int*)(fw + off); off += (size_t)NN * CAP0;
    float* vals0  = fw + off;         off += (size_t)NN * CAP0;
    int*   cols1  = (int*)(fw + off); off += (size_t)KK1 * CAP1;
    float* vals1  = fw + off;         off += (size_t)KK1 * CAP1;
    int*   cols2  = (int*)(fw + off); off += (size_t)KK2 * CAP2;
    float* vals2  = fw + off;         off += (size_t)KK2 * CAP2;
    int*   bc0C   = (int*)(fw + off); off += (size_t)NN * CAPB0;
    float* bc0V   = fw + off;         off += (size_t)NN * CAPB0;
    int*   bc0N   = (int*)(fw + off); off += NN;
    int*   bc1C   = (int*)(fw + off); off += (size_t)KK1 * CAPB1;
    float* bc1V   = fw + off;         off += (size_t)KK1 * CAPB1;
    int*   bc1N   = (int*)(fw + off); off += KK1;
    int*   cnt0   = (int*)(fw + off); off += NN;
    int*   cnt1   = (int*)(fw + off); off += KK1;
    int*   cnt2   = (int*)(fw + off); off += KK2 + 2;
    float* g      = fw + off; off += (size_t)NN * HIDC;
    float* res0   = fw + off; off += (size_t)NN * HIDC;
    float* res1   = fw + off; off += (size_t)KK1 * HIDC;
    float* hp     = fw + off; off += (size_t)KK1 * HIDC;
    float* hp2    = fw + off; off += (size_t)KK2 * HIDC;
    float* x2     = fw + off; off += (size_t)KK2 * HIDC;
    float* xu     = fw + off; off += (size_t)KK1 * HIDC;
    float* sc1    = fw + off; off += NN;
    float* sc2    = fw + off; off += KK1;
    float* dinv0  = fw + off; off += NN;
    float* dinv1  = fw + off; off += KK1;
    float* dinv2  = fw + off; off += KK2 + 2;
    int* perm1    = (int*)(fw + off); off += KK1;
    int* perm2    = (int*)(fw + off); off += KK2 + 2;
    int* selpos1  = (int*)(fw + off); off += NN;
    int* selpos2  = (int*)(fw + off); off += KK1;
    if (ws_size < off * sizeof(float)) return;

    dim3 b64(64), b256(256);

    // ---- CSR0 + dinv0 directly from edge list
    hipMemsetAsync(cntraw, 0, NN * sizeof(int), stream);
    k_edge_slots<<<dim3((EE + 255) / 256), b256, 0, stream>>>(ei, cntraw, slots);
    k_csr0_sort<<<dim3(NN / 4), b256, 0, stream>>>(cntraw, slots, cols0, vals0, cnt0, dinv0);

    // ---- GCN0 -> res0 (+score sc1)
    k_xw_scale<<<dim3(NN), b64, 0, stream>>>(x, nullptr, nullptr, W0, dinv0, g, NN, 16, 64);
    k_gcn_agg_csr<<<dim3(NN), b256, 0, stream>>>(cols0, vals0, cnt0, CAP0, g, dinv0, b0, res0, NN, 64, 1, p1, sc1);

    // ---- pool 1 (topk + pool fused), then sparse augment -> CSR1 + dinv1
    k_topk<<<dim3(NN), b256, 0, stream>>>(sc1, res0, NN, KK1, perm1, selpos1, hp);
    k_bcolcsr<<<dim3(NN / 4), b256, 0, stream>>>(cols0, vals0, cnt0, CAP0, selpos1, NN, bc0C, bc0V, bc0N, CAPB0);
    k_aug_sparse<<<dim3(KK1), b256, 0, stream>>>(perm1, cols0, vals0, cnt0, CAP0,
                                                 bc0C, bc0V, bc0N, CAPB0, KK1,
                                                 cols1, vals1, cnt1, dinv1, CAP1);

    // ---- GCN1 -> res1 (+score sc2)
    k_xw_scale<<<dim3(KK1), b64, 0, stream>>>(hp, nullptr, nullptr, W1, dinv1, g, KK1, 64, 64);
    k_gcn_agg_csr<<<dim3(KK1), b256, 0, stream>>>(cols1, vals1, cnt1, CAP1, g, dinv1, b1, res1, KK1, 64, 1, p2, sc2);

    // ---- pool 2, sparse augment -> CSR2 + dinv2
    k_topk<<<dim3(KK1), b256, 0, stream>>>(sc2, res1, KK1, KK2, perm2, selpos2, hp2);
    k_bcolcsr<<<dim3(KK1 / 4), b256, 0, stream>>>(cols1, vals1, cnt1, CAP1, selpos2, KK1, bc1C, bc1V, bc1N, CAPB1);
    k_aug_sparse<<<dim3(KK2), b256, 0, stream>>>(perm2, cols1, vals1, cnt1, CAP1,
                                                 bc1C, bc1V, bc1N, CAPB1, KK2,
                                                 cols2, vals2, cnt2, dinv2, CAP2);

    // ---- GCN2 -> x2
    k_xw_scale<<<dim3(KK2), b64, 0, stream>>>(hp2, nullptr, nullptr, W2, dinv2, g, KK2, 64, 64);
    k_gcn_agg_csr<<<dim3(KK2), b256, 0, stream>>>(cols2, vals2, cnt2, CAP2, g, dinv2, b2, x2, KK2, 64, 1, nullptr, nullptr);

    // ---- up to level 1: h = res1 + up(x2 via selpos2); GCN(Wu0) -> xu
    k_xw_scale<<<dim3(KK1), b64, 0, stream>>>(res1, x2, selpos2, Wu0, dinv1, g, KK1, 64, 64);
    k_gcn_agg_csr<<<dim3(KK1), b256, 0, stream>>>(cols1, vals1, cnt1, CAP1, g, dinv1, bu0, xu, KK1, 64, 1, nullptr, nullptr);

    // ---- up to level 0: h = res0 + up(xu via selpos1); GCN(Wu1) -> out (no tanh)
    k_xw_scale<<<dim3(NN), b64, 0, stream>>>(res0, xu, selpos1, Wu1, dinv0, g, NN, 64, 16);
    k_gcn_agg_csr<<<dim3(NN), b256, 0, stream>>>(cols0, vals0, cnt0, CAP0, g, dinv0, bu1, out, NN, 16, 0, nullptr, nullptr);
}

// Round 10
// 175.020 us; speedup vs baseline: 6.5510x; 1.0770x over previous
//
#include <hip/hip_runtime.h>

#define NN   3000
#define EE   48000
#define KK1  1500
#define KK2  750
#define KK2P 752      // padded row stride for Bcol2 (float4 alignment)
#define HIDC 64
#define SLOT 64       // max raw in-degree slots (mean 16; Poisson tail safe)

#define CAP0  64      // CSR0 row capacity
#define CAP1  768     // CSR1 row capacity
#define CAP2  768     // CSR2 row capacity (>=750: lossless)
#define CAPB0 64      // filtered-CSR capacity, level 0 -> 1
#define CAPMAX 768

// ---------------- kernels ----------------

// per-edge slot scatter: slots[t][idx] = s, idx = atomic count
__global__ void k_edge_slots(const int* __restrict__ ei, int* __restrict__ cntraw,
                             int* __restrict__ slots) {
    int e = blockIdx.x * blockDim.x + threadIdx.x;
    if (e >= EE) return;
    int s = ei[e];        // source
    int t = ei[EE + e];   // target
    int idx = atomicAdd(&cntraw[t], 1);
    if (idx < SLOT) slots[t * SLOT + idx] = s;
}

// wave per row: sort+dedup slot entries -> CSR0 (col asc, multiplicity vals) + dinv0.
__global__ void k_csr0_sort(const int* __restrict__ cntraw, const int* __restrict__ slots,
                            int* __restrict__ cols, float* __restrict__ vals,
                            int* __restrict__ cnt, float* __restrict__ dinv) {
    int row = blockIdx.x * (blockDim.x >> 6) + (threadIdx.x >> 6);   // 4 rows/block
    int lane = threadIdx.x & 63;
    int raw = cntraw[row];
    int nz = raw < SLOT ? raw : SLOT;
    int my = (lane < nz) ? slots[row * SLOT + lane] : 0x7FFFFFFF;
    int dup_before = 0, equal_total = 0;
    for (int f = 0; f < 64; ++f) {
        int cf = __shfl(my, f, 64);
        if (cf == my) { equal_total++; if (f < lane) dup_before++; }
    }
    bool leader = (lane < nz) && (dup_before == 0);
    unsigned long long lm = __ballot(leader);
    int dl = 0;
    unsigned long long m = lm;
    while (m) {                      // iterate leader lanes (wave-uniform sequence)
        int f = __builtin_ctzll(m); m &= m - 1;
        int cf = __shfl(my, f, 64);
        dl += (cf < my);
    }
    if (leader) {
        cols[(size_t)row * CAP0 + dl] = my;
        vals[(size_t)row * CAP0 + dl] = (float)equal_total;   // duplicate edges sum
    }
    if (lane == 0) {
        cnt[row] = __popcll(lm);
        dinv[row] = rsqrtf((float)raw + 2.0f);                // in-degree + self-loop wt 2
    }
}

// g[i,:] = dinv[i] * ((h[i,:] + up[selpos[i],:]) @ W); block=64, grid=n
__global__ void k_xw_scale(const float* __restrict__ h, const float* __restrict__ up,
                           const int* __restrict__ selpos,
                           const float* __restrict__ W, const float* __restrict__ dinv,
                           float* __restrict__ g, int n, int IC, int OC) {
    int row = blockIdx.x;
    int c = threadIdx.x;
    __shared__ float hr[64];
    if (c < IC) {
        float v = h[(size_t)row * IC + c];
        if (selpos) {
            int sp = selpos[row];
            if (sp >= 0) v += up[(size_t)sp * IC + c];
        }
        hr[c] = v;
    }
    __syncthreads();
    if (c >= OC) return;
    float acc = 0.0f;
    for (int k = 0; k < IC; ++k) acc += hr[k] * W[k * OC + c];
    g[(size_t)row * OC + c] = dinv[row] * acc;
}

// out[t,:] = act( dinv[t] * ( sum_e val_e * g[col_e,:] + 2*g[t,:] ) + b )
// Block per row, 4 waves split nonzeros (16-entry rounds, 4-ILP), LDS reduce;
// wave 0 finishes + optional fused TopK score (C==64).
__global__ void k_gcn_agg_csr(const int* __restrict__ cols, const float* __restrict__ vals,
                              const int* __restrict__ cnt, int CAP,
                              const float* __restrict__ g, const float* __restrict__ dinv,
                              const float* __restrict__ bias, float* __restrict__ out,
                              int n, int C, int do_tanh,
                              const float* __restrict__ p, float* __restrict__ score) {
    int row = blockIdx.x;
    int w = threadIdx.x >> 6;
    int lane = threadIdx.x & 63;
    int nz = cnt[row];
    const int*   rc = cols + (size_t)row * CAP;
    const float* rv = vals + (size_t)row * CAP;
    bool act = lane < C;
    float a0 = 0.f, a1 = 0.f, a2 = 0.f, a3 = 0.f;
    for (int e = 4 * w; e + 4 <= nz; e += 16) {
        int   c0 = rc[e], c1 = rc[e + 1], c2 = rc[e + 2], c3 = rc[e + 3];
        float v0 = rv[e], v1 = rv[e + 1], v2 = rv[e + 2], v3 = rv[e + 3];
        if (act) {
            a0 += v0 * g[(size_t)c0 * C + lane];
            a1 += v1 * g[(size_t)c1 * C + lane];
            a2 += v2 * g[(size_t)c2 * C + lane];
            a3 += v3 * g[(size_t)c3 * C + lane];
        }
    }
    if (w == 0) {  // tail (< 4 entries)
        for (int e = nz & ~3; e < nz; ++e)
            if (act) a0 += rv[e] * g[(size_t)rc[e] * C + lane];
    }
    __shared__ float red[4][64];
    red[w][lane] = (a0 + a1) + (a2 + a3);
    __syncthreads();
    if (w == 0) {
        float o = 0.f;
        if (act) {
            float a = (red[0][lane] + red[1][lane]) + (red[2][lane] + red[3][lane])
                    + 2.0f * g[(size_t)row * C + lane];
            o = dinv[row] * a + bias[lane];
            if (do_tanh) o = tanhf(o);
            out[(size_t)row * C + lane] = o;
        }
        if (p) {  // fused score = tanh((row . p) * rsqrt(p.p)); C==64 here
            float pv = p[lane];
            float d = o * pv, pp = pv * pv;
            for (int off = 32; off; off >>= 1) {
                d  += __shfl_down(d, off, 64);
                pp += __shfl_down(pp, off, 64);
            }
            if (lane == 0) score[row] = tanhf(d * rsqrtf(pp));
        }
    }
}

// exact jax.lax.top_k order (value desc, index asc), rank-count; fused pool:
// block per candidate i; selpos[i] = rank (or -1); if selected, writes
// hp[rank,:] = h[i,:] * score[i].
__global__ void k_topk(const float* __restrict__ score, const float* __restrict__ h,
                       int n, int k, int* __restrict__ perm, int* __restrict__ selpos,
                       float* __restrict__ hp) {
    int i = blockIdx.x;
    float si = score[i];
    int r = 0;
    for (int j = threadIdx.x; j < n; j += blockDim.x) {
        float sj = score[j];
        r += (sj > si) || (sj == si && j < i);
    }
    int lane = threadIdx.x & 63, wid = threadIdx.x >> 6;
    for (int off = 32; off; off >>= 1) r += __shfl_down(r, off, 64);
    __shared__ int red[4];
    __shared__ int srank;
    if (lane == 0) red[wid] = r;
    __syncthreads();
    if (threadIdx.x == 0) {
        int rank = red[0] + red[1] + red[2] + red[3];
        srank = rank;
        selpos[i] = (rank < k) ? rank : -1;
        if (rank < k) perm[rank] = i;
    }
    __syncthreads();
    int rank = srank;
    if (rank < k && threadIdx.x < HIDC)
        hp[(size_t)rank * HIDC + threadIdx.x] = h[(size_t)i * HIDC + threadIdx.x] * si;
}

// Filtered CSR of B (= T offdiag + I) restricted to selected columns, remapped
// to compact j indices. Wave per row (4/block). Col-ascending, deterministic.
__global__ void k_bcolcsr(const int* __restrict__ cols, const float* __restrict__ vals,
                          const int* __restrict__ cnt, int CAPS,
                          const int* __restrict__ selpos, int n,
                          int* __restrict__ bcC, float* __restrict__ bcV,
                          int* __restrict__ bcN, int CAPB) {
    int row = blockIdx.x * (blockDim.x >> 6) + (threadIdx.x >> 6);
    int lane = threadIdx.x & 63;
    if (row >= n) return;
    int nz = cnt[row];
    int base = 0;
    for (int e0 = 0; e0 < nz; e0 += 64) {
        int e = e0 + lane;
        int j = -1; float v = 0.0f;
        if (e < nz) {
            int c = cols[(size_t)row * CAPS + e];
            if (c != row) { j = selpos[c]; v = vals[(size_t)row * CAPS + e]; }
        }
        unsigned long long mb = __ballot(j >= 0);
        if (j >= 0) {
            int idx = base + __popcll(mb & ((1ull << lane) - 1ull));
            if (idx < CAPB) { bcC[(size_t)row * CAPB + idx] = j; bcV[(size_t)row * CAPB + idx] = v; }
        }
        base += __popcll(mb);
    }
    if (lane == 0) {
        int jd = selpos[row];
        if (jd >= 0 && base < CAPB) {
            bcC[(size_t)row * CAPB + base] = jd;
            bcV[(size_t)row * CAPB + base] = 1.0f;     // B diag = 1
            base++;
        }
        bcN[row] = base < CAPB ? base : CAPB;
    }
}

// Sparse x sparse augment (used at level 0->1 where nz is tiny ~16):
// dense LDS row via atomicAdd (exact integers -> order-independent), then
// diag zero, rowsum -> dinv, wave-0 ballot compaction to CSR.
__global__ void k_aug_sparse(const int* __restrict__ perm,
                             const int* __restrict__ colsS, const float* __restrict__ valsS,
                             const int* __restrict__ cntS, int CAPS,
                             const int* __restrict__ bcC, const float* __restrict__ bcV,
                             const int* __restrict__ bcN, int CAPB, int kk,
                             int* __restrict__ colsD, float* __restrict__ valsD,
                             int* __restrict__ cntD, float* __restrict__ dinvD, int CAPD) {
    __shared__ float srow[1504];
    __shared__ float ssum[4];
    int i = blockIdx.x;
    int pi = perm[i];
    int nzS = cntS[pi];
    for (int t = threadIdx.x; t < 1504; t += blockDim.x) srow[t] = 0.0f;
    __syncthreads();
    int w = threadIdx.x >> 6, lane = threadIdx.x & 63;
    // ee in [0, nzS]; ee == nzS is the implicit diag entry (k=pi, val=1)
    for (int ee = w; ee <= nzS; ee += 4) {
        int k; float kv;
        if (ee == nzS) { k = pi; kv = 1.0f; }
        else {
            k = colsS[(size_t)pi * CAPS + ee];
            if (k == pi) continue;               // original diag replaced by implicit 1
            kv = valsS[(size_t)pi * CAPS + ee];
        }
        int bn = bcN[k];
        const int*   bc = bcC + (size_t)k * CAPB;
        const float* bv = bcV + (size_t)k * CAPB;
        for (int t = lane; t < bn; t += 64)
            atomicAdd(&srow[bc[t]], kv * bv[t]);
    }
    __syncthreads();
    if (threadIdx.x == 0) srow[i] = 0.0f;        // zero output diag
    __syncthreads();
    float psum = 0.0f;
    for (int t = threadIdx.x; t < kk; t += blockDim.x) psum += srow[t];
    for (int off = 32; off; off >>= 1) psum += __shfl_down(psum, off, 64);
    if (lane == 0) ssum[w] = psum;
    __syncthreads();
    if (w == 0) {
        if (lane == 0)
            dinvD[i] = rsqrtf((ssum[0] + ssum[1]) + (ssum[2] + ssum[3]) + 2.0f);
        int base = 0;
        for (int c0 = 0; c0 < kk; c0 += 64) {
            int c = c0 + lane;
            float v = (c < kk) ? srow[c] : 0.0f;
            unsigned long long mb = __ballot(v != 0.0f);
            if (v != 0.0f) {
                int idx = base + __popcll(mb & ((1ull << lane) - 1ull));
                if (idx < CAPD) {
                    colsD[(size_t)i * CAPD + idx] = c;
                    valsD[(size_t)i * CAPD + idx] = v;
                }
            }
            base += __popcll(mb);
        }
        if (lane == 0) cntD[i] = base < CAPD ? base : CAPD;
    }
}

// Dense Bcol panel: Bcol[row][j] = B[row, perm[j]] (diag forced 1); pre-zeroed.
__global__ void k_bcol_scatter(const int* __restrict__ cols, const float* __restrict__ vals,
                               const int* __restrict__ cnt, int CAP,
                               const int* __restrict__ selpos, float* __restrict__ Bcol, int ldb) {
    int row = blockIdx.x;
    int nz = cnt[row];
    for (int e = threadIdx.x; e < nz; e += blockDim.x) {
        int c = cols[(size_t)row * CAP + e];
        if (c == row) continue;                 // diag handled below
        int j = selpos[c];
        if (j >= 0) Bcol[(size_t)row * ldb + j] = vals[(size_t)row * CAP + e];
    }
    if (threadIdx.x == 0) {
        int j = selpos[row];
        if (j >= 0) Bcol[(size_t)row * ldb + j] = 1.0f;  // B diag = 1
    }
}

// Dense-gather augment + in-LDS CSR compaction (used at level 1->2):
// row i of Tdst = B[perm[i],:] @ Bcol, 4-ILP float4 gather; rowsum -> dinv;
// wave 0 ballot-compacts LDS row to CSR. Dense Tdst never hits global.
__global__ void k_aug_fused(const int* __restrict__ perm,
                            const int* __restrict__ colsS, const float* __restrict__ valsS,
                            const int* __restrict__ cntS, int CAPS,
                            const float* __restrict__ Bcol, int ldb, int kk,
                            int* __restrict__ colsD, float* __restrict__ valsD,
                            int* __restrict__ cntD, float* __restrict__ dinvD, int CAPD) {
    __shared__ int   scol[CAPMAX];
    __shared__ float sval[CAPMAX];
    __shared__ float srow[1504];
    __shared__ float ssum[4];
    int i = blockIdx.x;
    int pi = perm[i];
    int nz = cntS[pi];
    for (int e = threadIdx.x; e < nz; e += blockDim.x) {
        int c = colsS[(size_t)pi * CAPS + e];
        scol[e] = c;
        sval[e] = (c == pi) ? 0.0f : valsS[(size_t)pi * CAPS + e];  // diag via Bcol[pi] term
    }
    __syncthreads();
    float psum = 0.0f;
    for (int j0 = threadIdx.x * 4; j0 < kk; j0 += blockDim.x * 4) {
        int j4 = j0 >> 2;
        float4 a = ((const float4*)(Bcol + (size_t)pi * ldb))[j4];   // 1 * B[pi, perm[j..j+3]]
        int e = 0;
        for (; e + 4 <= nz; e += 4) {
            float v0 = sval[e], v1 = sval[e + 1], v2 = sval[e + 2], v3 = sval[e + 3];
            float4 b0 = ((const float4*)(Bcol + (size_t)scol[e]     * ldb))[j4];
            float4 b1 = ((const float4*)(Bcol + (size_t)scol[e + 1] * ldb))[j4];
            float4 b2 = ((const float4*)(Bcol + (size_t)scol[e + 2] * ldb))[j4];
            float4 b3 = ((const float4*)(Bcol + (size_t)scol[e + 3] * ldb))[j4];
            a.x += v0 * b0.x + v1 * b1.x + v2 * b2.x + v3 * b3.x;
            a.y += v0 * b0.y + v1 * b1.y + v2 * b2.y + v3 * b3.y;
            a.z += v0 * b0.z + v1 * b1.z + v2 * b2.z + v3 * b3.z;
            a.w += v0 * b0.w + v1 * b1.w + v2 * b2.w + v3 * b3.w;
        }
        for (; e < nz; ++e) {
            float v = sval[e];
            float4 b = ((const float4*)(Bcol + (size_t)scol[e] * ldb))[j4];
            a.x += v * b.x; a.y += v * b.y; a.z += v * b.z; a.w += v * b.w;
        }
        if (i >= j0 && i < j0 + 4) ((float*)&a)[i - j0] = 0.0f;      // zero output diag
        *(float4*)(srow + j0) = a;
        psum += (a.x + a.y) + (a.z + a.w);
    }
    int lane = threadIdx.x & 63, w = threadIdx.x >> 6;
    for (int off = 32; off; off >>= 1) psum += __shfl_down(psum, off, 64);
    if (lane == 0) ssum[w] = psum;
    __syncthreads();
    if (w == 0) {
        if (lane == 0)
            dinvD[i] = rsqrtf((ssum[0] + ssum[1]) + (ssum[2] + ssum[3]) + 2.0f);
        int base = 0;
        for (int c0 = 0; c0 < kk; c0 += 64) {
            int c = c0 + lane;
            float v = (c < kk) ? srow[c] : 0.0f;
            unsigned long long mb = __ballot(v != 0.0f);
            if (v != 0.0f) {
                int idx = base + __popcll(mb & ((1ull << lane) - 1ull));
                if (idx < CAPD) {
                    colsD[(size_t)i * CAPD + idx] = c;
                    valsD[(size_t)i * CAPD + idx] = v;
                }
            }
            base += __popcll(mb);
        }
        if (lane == 0) cntD[i] = base < CAPD ? base : CAPD;
    }
}

// ---------------- launch ----------------

extern "C" void kernel_launch(void* const* d_in, const int* in_sizes, int n_in,
                              void* d_out, int out_size, void* d_ws, size_t ws_size,
                              hipStream_t stream) {
    const float* x   = (const float*)d_in[0];
    const int*   ei  = (const int*)d_in[1];
    const float* W0  = (const float*)d_in[2];
    const float* b0  = (const float*)d_in[3];
    const float* W1  = (const float*)d_in[4];
    const float* b1  = (const float*)d_in[5];
    const float* W2  = (const float*)d_in[6];
    const float* b2  = (const float*)d_in[7];
    const float* p1  = (const float*)d_in[8];
    const float* p2  = (const float*)d_in[9];
    const float* Wu0 = (const float*)d_in[10];
    const float* bu0 = (const float*)d_in[11];
    const float* Wu1 = (const float*)d_in[12];
    const float* bu1 = (const float*)d_in[13];
    float* out = (float*)d_out;

    // ---- workspace layout (float units) ----
    float* fw = (float*)d_ws;
    size_t off = 0;
    int*   slots  = (int*)(fw + off); off += (size_t)NN * SLOT;
    int*   cntraw = (int*)(fw + off); off += NN;
    int*   cols0  = (int*)(fw + off); off += (size_t)NN * CAP0;
    float* vals0  = fw + off;         off += (size_t)NN * CAP0;
    int*   cols1  = (int*)(fw + off); off += (size_t)KK1 * CAP1;
    float* vals1  = fw + off;         off += (size_t)KK1 * CAP1;
    int*   cols2  = (int*)(fw + off); off += (size_t)KK2 * CAP2;
    float* vals2  = fw + off;         off += (size_t)KK2 * CAP2;
    int*   bc0C   = (int*)(fw + off); off += (size_t)NN * CAPB0;
    float* bc0V   = fw + off;         off += (size_t)NN * CAPB0;
    int*   bc0N   = (int*)(fw + off); off += NN;
    float* Bcol2  = fw + off;         off += (size_t)KK1 * KK2P;
    int*   cnt0   = (int*)(fw + off); off += NN;
    int*   cnt1   = (int*)(fw + off); off += KK1;
    int*   cnt2   = (int*)(fw + off); off += KK2 + 2;
    float* g      = fw + off; off += (size_t)NN * HIDC;
    float* res0   = fw + off; off += (size_t)NN * HIDC;
    float* res1   = fw + off; off += (size_t)KK1 * HIDC;
    float* hp     = fw + off; off += (size_t)KK1 * HIDC;
    float* hp2    = fw + off; off += (size_t)KK2 * HIDC;
    float* x2     = fw + off; off += (size_t)KK2 * HIDC;
    float* xu     = fw + off; off += (size_t)KK1 * HIDC;
    float* sc1    = fw + off; off += NN;
    float* sc2    = fw + off; off += KK1;
    float* dinv0  = fw + off; off += NN;
    float* dinv1  = fw + off; off += KK1;
    float* dinv2  = fw + off; off += KK2 + 2;
    int* perm1    = (int*)(fw + off); off += KK1;
    int* perm2    = (int*)(fw + off); off += KK2 + 2;
    int* selpos1  = (int*)(fw + off); off += NN;
    int* selpos2  = (int*)(fw + off); off += KK1;
    if (ws_size < off * sizeof(float)) return;

    dim3 b64(64), b256(256);

    // ---- CSR0 + dinv0 directly from edge list
    hipMemsetAsync(cntraw, 0, NN * sizeof(int), stream);
    k_edge_slots<<<dim3((EE + 255) / 256), b256, 0, stream>>>(ei, cntraw, slots);
    k_csr0_sort<<<dim3(NN / 4), b256, 0, stream>>>(cntraw, slots, cols0, vals0, cnt0, dinv0);

    // ---- GCN0 -> res0 (+score sc1)
    k_xw_scale<<<dim3(NN), b64, 0, stream>>>(x, nullptr, nullptr, W0, dinv0, g, NN, 16, 64);
    k_gcn_agg_csr<<<dim3(NN), b256, 0, stream>>>(cols0, vals0, cnt0, CAP0, g, dinv0, b0, res0, NN, 64, 1, p1, sc1);

    // ---- pool 1 (topk + pool fused), then sparse augment -> CSR1 + dinv1
    k_topk<<<dim3(NN), b256, 0, stream>>>(sc1, res0, NN, KK1, perm1, selpos1, hp);
    k_bcolcsr<<<dim3(NN / 4), b256, 0, stream>>>(cols0, vals0, cnt0, CAP0, selpos1, NN, bc0C, bc0V, bc0N, CAPB0);
    k_aug_sparse<<<dim3(KK1), b256, 0, stream>>>(perm1, cols0, vals0, cnt0, CAP0,
                                                 bc0C, bc0V, bc0N, CAPB0, KK1,
                                                 cols1, vals1, cnt1, dinv1, CAP1);

    // ---- GCN1 -> res1 (+score sc2)
    k_xw_scale<<<dim3(KK1), b64, 0, stream>>>(hp, nullptr, nullptr, W1, dinv1, g, KK1, 64, 64);
    k_gcn_agg_csr<<<dim3(KK1), b256, 0, stream>>>(cols1, vals1, cnt1, CAP1, g, dinv1, b1, res1, KK1, 64, 1, p2, sc2);

    // ---- pool 2, dense-gather augment -> CSR2 + dinv2
    k_topk<<<dim3(KK1), b256, 0, stream>>>(sc2, res1, KK1, KK2, perm2, selpos2, hp2);
    hipMemsetAsync(Bcol2, 0, (size_t)KK1 * KK2P * sizeof(float), stream);
    k_bcol_scatter<<<dim3(KK1), b64, 0, stream>>>(cols1, vals1, cnt1, CAP1, selpos2, Bcol2, KK2P);
    k_aug_fused<<<dim3(KK2), b256, 0, stream>>>(perm2, cols1, vals1, cnt1, CAP1,
                                                Bcol2, KK2P, KK2, cols2, vals2, cnt2, dinv2, CAP2);

    // ---- GCN2 -> x2
    k_xw_scale<<<dim3(KK2), b64, 0, stream>>>(hp2, nullptr, nullptr, W2, dinv2, g, KK2, 64, 64);
    k_gcn_agg_csr<<<dim3(KK2), b256, 0, stream>>>(cols2, vals2, cnt2, CAP2, g, dinv2, b2, x2, KK2, 64, 1, nullptr, nullptr);

    // ---- up to level 1: h = res1 + up(x2 via selpos2); GCN(Wu0) -> xu
    k_xw_scale<<<dim3(KK1), b64, 0, stream>>>(res1, x2, selpos2, Wu0, dinv1, g, KK1, 64, 64);
    k_gcn_agg_csr<<<dim3(KK1), b256, 0, stream>>>(cols1, vals1, cnt1, CAP1, g, dinv1, bu0, xu, KK1, 64, 1, nullptr, nullptr);

    // ---- up to level 0: h = res0 + up(xu via selpos1); GCN(Wu1) -> out (no tanh)
    k_xw_scale<<<dim3(NN), b64, 0, stream>>>(res0, xu, selpos1, Wu1, dinv0, g, NN, 64, 16);
    k_gcn_agg_csr<<<dim3(NN), b256, 0, stream>>>(cols0, vals0, cnt0, CAP0, g, dinv0, bu1, out, NN, 16, 0, nullptr, nullptr);
}

// Round 11
// 165.038 us; speedup vs baseline: 6.9472x; 1.0605x over previous
//
#include <hip/hip_runtime.h>

#define NN   3000
#define EE   48000
#define KK1  1500
#define KK2  750
#define KK2P 752      // padded row stride for Bcol2 (float4 alignment)
#define HIDC 64
#define SLOT 64       // max raw in-degree slots (mean 16; Poisson tail safe)

#define CAP0  64      // CSR0 row capacity
#define CAP1  768     // CSR1 row capacity
#define CAP2  768     // CSR2 row capacity (>=750: lossless)
#define CAPB0 64      // filtered-CSR capacity, level 0 -> 1
#define CAPMAX 768

// ---------------- kernels ----------------

// per-edge slot scatter: slots[t][idx] = s, idx = atomic count
__global__ void k_edge_slots(const int* __restrict__ ei, int* __restrict__ cntraw,
                             int* __restrict__ slots) {
    int e = blockIdx.x * blockDim.x + threadIdx.x;
    if (e >= EE) return;
    int s = ei[e];        // source
    int t = ei[EE + e];   // target
    int idx = atomicAdd(&cntraw[t], 1);
    if (idx < SLOT) slots[t * SLOT + idx] = s;
}

// wave per row: sort+dedup slot entries -> CSR0 (col asc, multiplicity vals) + dinv0.
__global__ void k_csr0_sort(const int* __restrict__ cntraw, const int* __restrict__ slots,
                            int* __restrict__ cols, float* __restrict__ vals,
                            int* __restrict__ cnt, float* __restrict__ dinv) {
    int row = blockIdx.x * (blockDim.x >> 6) + (threadIdx.x >> 6);   // 4 rows/block
    int lane = threadIdx.x & 63;
    int raw = cntraw[row];
    int nz = raw < SLOT ? raw : SLOT;
    int my = (lane < nz) ? slots[row * SLOT + lane] : 0x7FFFFFFF;
    int dup_before = 0, equal_total = 0;
    for (int f = 0; f < 64; ++f) {
        int cf = __shfl(my, f, 64);
        if (cf == my) { equal_total++; if (f < lane) dup_before++; }
    }
    bool leader = (lane < nz) && (dup_before == 0);
    unsigned long long lm = __ballot(leader);
    int dl = 0;
    unsigned long long m = lm;
    while (m) {                      // iterate leader lanes (wave-uniform sequence)
        int f = __builtin_ctzll(m); m &= m - 1;
        int cf = __shfl(my, f, 64);
        dl += (cf < my);
    }
    if (leader) {
        cols[(size_t)row * CAP0 + dl] = my;
        vals[(size_t)row * CAP0 + dl] = (float)equal_total;   // duplicate edges sum
    }
    if (lane == 0) {
        cnt[row] = __popcll(lm);
        dinv[row] = rsqrtf((float)raw + 2.0f);                // in-degree + self-loop wt 2
    }
}

// g[i,:] = dinv[i] * ((h[i,:] + up[selpos[i],:]) @ W); block=64, grid=n
__global__ void k_xw_scale(const float* __restrict__ h, const float* __restrict__ up,
                           const int* __restrict__ selpos,
                           const float* __restrict__ W, const float* __restrict__ dinv,
                           float* __restrict__ g, int n, int IC, int OC) {
    int row = blockIdx.x;
    int c = threadIdx.x;
    __shared__ float hr[64];
    if (c < IC) {
        float v = h[(size_t)row * IC + c];
        if (selpos) {
            int sp = selpos[row];
            if (sp >= 0) v += up[(size_t)sp * IC + c];
        }
        hr[c] = v;
    }
    __syncthreads();
    if (c >= OC) return;
    float acc = 0.0f;
    for (int k = 0; k < IC; ++k) acc += hr[k] * W[k * OC + c];
    g[(size_t)row * OC + c] = dinv[row] * acc;
}

// out[t,:] = act( dinv[t] * ( sum_e val_e * g[col_e,:] + 2*g[t,:] ) + b )
// Block per row, 4 waves split nonzeros (32-entry rounds, 8-ILP), LDS reduce;
// wave 0 finishes + optional fused TopK score (C==64).
__global__ void k_gcn_agg_csr(const int* __restrict__ cols, const float* __restrict__ vals,
                              const int* __restrict__ cnt, int CAP,
                              const float* __restrict__ g, const float* __restrict__ dinv,
                              const float* __restrict__ bias, float* __restrict__ out,
                              int n, int C, int do_tanh,
                              const float* __restrict__ p, float* __restrict__ score) {
    int row = blockIdx.x;
    int w = threadIdx.x >> 6;
    int lane = threadIdx.x & 63;
    int nz = cnt[row];
    const int*   rc = cols + (size_t)row * CAP;
    const float* rv = vals + (size_t)row * CAP;
    bool act = lane < C;
    float a0 = 0.f, a1 = 0.f, a2 = 0.f, a3 = 0.f;
    float a4 = 0.f, a5 = 0.f, a6 = 0.f, a7 = 0.f;
    for (int e = 8 * w; e + 8 <= nz; e += 32) {
        int   c0 = rc[e],     c1 = rc[e + 1], c2 = rc[e + 2], c3 = rc[e + 3];
        int   c4 = rc[e + 4], c5 = rc[e + 5], c6 = rc[e + 6], c7 = rc[e + 7];
        float v0 = rv[e],     v1 = rv[e + 1], v2 = rv[e + 2], v3 = rv[e + 3];
        float v4 = rv[e + 4], v5 = rv[e + 5], v6 = rv[e + 6], v7 = rv[e + 7];
        if (act) {
            a0 += v0 * g[(size_t)c0 * C + lane];
            a1 += v1 * g[(size_t)c1 * C + lane];
            a2 += v2 * g[(size_t)c2 * C + lane];
            a3 += v3 * g[(size_t)c3 * C + lane];
            a4 += v4 * g[(size_t)c4 * C + lane];
            a5 += v5 * g[(size_t)c5 * C + lane];
            a6 += v6 * g[(size_t)c6 * C + lane];
            a7 += v7 * g[(size_t)c7 * C + lane];
        }
    }
    if (w == 0) {  // tail (< 8 entries)
        for (int e = nz & ~7; e < nz; ++e)
            if (act) a0 += rv[e] * g[(size_t)rc[e] * C + lane];
    }
    __shared__ float red[4][64];
    red[w][lane] = ((a0 + a1) + (a2 + a3)) + ((a4 + a5) + (a6 + a7));
    __syncthreads();
    if (w == 0) {
        float o = 0.f;
        if (act) {
            float a = (red[0][lane] + red[1][lane]) + (red[2][lane] + red[3][lane])
                    + 2.0f * g[(size_t)row * C + lane];
            o = dinv[row] * a + bias[lane];
            if (do_tanh) o = tanhf(o);
            out[(size_t)row * C + lane] = o;
        }
        if (p) {  // fused score = tanh((row . p) * rsqrt(p.p)); C==64 here
            float pv = p[lane];
            float d = o * pv, pp = pv * pv;
            for (int off = 32; off; off >>= 1) {
                d  += __shfl_down(d, off, 64);
                pp += __shfl_down(pp, off, 64);
            }
            if (lane == 0) score[row] = tanhf(d * rsqrtf(pp));
        }
    }
}

// exact jax.lax.top_k order (value desc, index asc), rank-count; fused pool:
// block per candidate i; selpos[i] = rank (or -1); if selected, writes
// hp[rank,:] = h[i,:] * score[i].
__global__ void k_topk(const float* __restrict__ score, const float* __restrict__ h,
                       int n, int k, int* __restrict__ perm, int* __restrict__ selpos,
                       float* __restrict__ hp) {
    int i = blockIdx.x;
    float si = score[i];
    int r = 0;
    for (int j = threadIdx.x; j < n; j += blockDim.x) {
        float sj = score[j];
        r += (sj > si) || (sj == si && j < i);
    }
    int lane = threadIdx.x & 63, wid = threadIdx.x >> 6;
    for (int off = 32; off; off >>= 1) r += __shfl_down(r, off, 64);
    __shared__ int red[4];
    __shared__ int srank;
    if (lane == 0) red[wid] = r;
    __syncthreads();
    if (threadIdx.x == 0) {
        int rank = red[0] + red[1] + red[2] + red[3];
        srank = rank;
        selpos[i] = (rank < k) ? rank : -1;
        if (rank < k) perm[rank] = i;
    }
    __syncthreads();
    int rank = srank;
    if (rank < k && threadIdx.x < HIDC)
        hp[(size_t)rank * HIDC + threadIdx.x] = h[(size_t)i * HIDC + threadIdx.x] * si;
}

// Filtered CSR of B (= T offdiag + I) restricted to selected columns, remapped
// to compact j indices. Wave per row (4/block). Col-ascending, deterministic.
__global__ void k_bcolcsr(const int* __restrict__ cols, const float* __restrict__ vals,
                          const int* __restrict__ cnt, int CAPS,
                          const int* __restrict__ selpos, int n,
                          int* __restrict__ bcC, float* __restrict__ bcV,
                          int* __restrict__ bcN, int CAPB) {
    int row = blockIdx.x * (blockDim.x >> 6) + (threadIdx.x >> 6);
    int lane = threadIdx.x & 63;
    if (row >= n) return;
    int nz = cnt[row];
    int base = 0;
    for (int e0 = 0; e0 < nz; e0 += 64) {
        int e = e0 + lane;
        int j = -1; float v = 0.0f;
        if (e < nz) {
            int c = cols[(size_t)row * CAPS + e];
            if (c != row) { j = selpos[c]; v = vals[(size_t)row * CAPS + e]; }
        }
        unsigned long long mb = __ballot(j >= 0);
        if (j >= 0) {
            int idx = base + __popcll(mb & ((1ull << lane) - 1ull));
            if (idx < CAPB) { bcC[(size_t)row * CAPB + idx] = j; bcV[(size_t)row * CAPB + idx] = v; }
        }
        base += __popcll(mb);
    }
    if (lane == 0) {
        int jd = selpos[row];
        if (jd >= 0 && base < CAPB) {
            bcC[(size_t)row * CAPB + base] = jd;
            bcV[(size_t)row * CAPB + base] = 1.0f;     // B diag = 1
            base++;
        }
        bcN[row] = base < CAPB ? base : CAPB;
    }
}

// Sparse x sparse augment (used at level 0->1 where nz is tiny ~16):
// dense LDS row via atomicAdd (exact integers -> order-independent), then
// diag zero, rowsum -> dinv, wave-0 ballot compaction to CSR.
__global__ void k_aug_sparse(const int* __restrict__ perm,
                             const int* __restrict__ colsS, const float* __restrict__ valsS,
                             const int* __restrict__ cntS, int CAPS,
                             const int* __restrict__ bcC, const float* __restrict__ bcV,
                             const int* __restrict__ bcN, int CAPB, int kk,
                             int* __restrict__ colsD, float* __restrict__ valsD,
                             int* __restrict__ cntD, float* __restrict__ dinvD, int CAPD) {
    __shared__ float srow[1504];
    __shared__ float ssum[4];
    int i = blockIdx.x;
    int pi = perm[i];
    int nzS = cntS[pi];
    for (int t = threadIdx.x; t < 1504; t += blockDim.x) srow[t] = 0.0f;
    __syncthreads();
    int w = threadIdx.x >> 6, lane = threadIdx.x & 63;
    // ee in [0, nzS]; ee == nzS is the implicit diag entry (k=pi, val=1)
    for (int ee = w; ee <= nzS; ee += 4) {
        int k; float kv;
        if (ee == nzS) { k = pi; kv = 1.0f; }
        else {
            k = colsS[(size_t)pi * CAPS + ee];
            if (k == pi) continue;               // original diag replaced by implicit 1
            kv = valsS[(size_t)pi * CAPS + ee];
        }
        int bn = bcN[k];
        const int*   bc = bcC + (size_t)k * CAPB;
        const float* bv = bcV + (size_t)k * CAPB;
        for (int t = lane; t < bn; t += 64)
            atomicAdd(&srow[bc[t]], kv * bv[t]);
    }
    __syncthreads();
    if (threadIdx.x == 0) srow[i] = 0.0f;        // zero output diag
    __syncthreads();
    float psum = 0.0f;
    for (int t = threadIdx.x; t < kk; t += blockDim.x) psum += srow[t];
    for (int off = 32; off; off >>= 1) psum += __shfl_down(psum, off, 64);
    if (lane == 0) ssum[w] = psum;
    __syncthreads();
    if (w == 0) {
        if (lane == 0)
            dinvD[i] = rsqrtf((ssum[0] + ssum[1]) + (ssum[2] + ssum[3]) + 2.0f);
        int base = 0;
        for (int c0 = 0; c0 < kk; c0 += 64) {
            int c = c0 + lane;
            float v = (c < kk) ? srow[c] : 0.0f;
            unsigned long long mb = __ballot(v != 0.0f);
            if (v != 0.0f) {
                int idx = base + __popcll(mb & ((1ull << lane) - 1ull));
                if (idx < CAPD) {
                    colsD[(size_t)i * CAPD + idx] = c;
                    valsD[(size_t)i * CAPD + idx] = v;
                }
            }
            base += __popcll(mb);
        }
        if (lane == 0) cntD[i] = base < CAPD ? base : CAPD;
    }
}

// Dense Bcol panel: Bcol[row][j] = B[row, perm[j]] (diag forced 1); pre-zeroed.
__global__ void k_bcol_scatter(const int* __restrict__ cols, const float* __restrict__ vals,
                               const int* __restrict__ cnt, int CAP,
                               const int* __restrict__ selpos, float* __restrict__ Bcol, int ldb) {
    int row = blockIdx.x;
    int nz = cnt[row];
    for (int e = threadIdx.x; e < nz; e += blockDim.x) {
        int c = cols[(size_t)row * CAP + e];
        if (c == row) continue;                 // diag handled below
        int j = selpos[c];
        if (j >= 0) Bcol[(size_t)row * ldb + j] = vals[(size_t)row * CAP + e];
    }
    if (threadIdx.x == 0) {
        int j = selpos[row];
        if (j >= 0) Bcol[(size_t)row * ldb + j] = 1.0f;  // B diag = 1
    }
}

// Dense-gather augment + in-LDS CSR compaction (used at level 1->2):
// row i of Tdst = B[perm[i],:] @ Bcol, 8-ILP float4 gather; rowsum -> dinv;
// wave 0 ballot-compacts LDS row to CSR. Dense Tdst never hits global.
__global__ void k_aug_fused(const int* __restrict__ perm,
                            const int* __restrict__ colsS, const float* __restrict__ valsS,
                            const int* __restrict__ cntS, int CAPS,
                            const float* __restrict__ Bcol, int ldb, int kk,
                            int* __restrict__ colsD, float* __restrict__ valsD,
                            int* __restrict__ cntD, float* __restrict__ dinvD, int CAPD) {
    __shared__ int   scol[CAPMAX];
    __shared__ float sval[CAPMAX];
    __shared__ float srow[1504];
    __shared__ float ssum[4];
    int i = blockIdx.x;
    int pi = perm[i];
    int nz = cntS[pi];
    for (int e = threadIdx.x; e < nz; e += blockDim.x) {
        int c = colsS[(size_t)pi * CAPS + e];
        scol[e] = c;
        sval[e] = (c == pi) ? 0.0f : valsS[(size_t)pi * CAPS + e];  // diag via Bcol[pi] term
    }
    __syncthreads();
    float psum = 0.0f;
    for (int j0 = threadIdx.x * 4; j0 < kk; j0 += blockDim.x * 4) {
        int j4 = j0 >> 2;
        float4 a = ((const float4*)(Bcol + (size_t)pi * ldb))[j4];   // 1 * B[pi, perm[j..j+3]]
        float4 acc1 = {0.f, 0.f, 0.f, 0.f};
        int e = 0;
        for (; e + 8 <= nz; e += 8) {
            float v0 = sval[e],     v1 = sval[e + 1], v2 = sval[e + 2], v3 = sval[e + 3];
            float v4 = sval[e + 4], v5 = sval[e + 5], v6 = sval[e + 6], v7 = sval[e + 7];
            float4 b0 = ((const float4*)(Bcol + (size_t)scol[e]     * ldb))[j4];
            float4 b1 = ((const float4*)(Bcol + (size_t)scol[e + 1] * ldb))[j4];
            float4 b2 = ((const float4*)(Bcol + (size_t)scol[e + 2] * ldb))[j4];
            float4 b3 = ((const float4*)(Bcol + (size_t)scol[e + 3] * ldb))[j4];
            float4 b4 = ((const float4*)(Bcol + (size_t)scol[e + 4] * ldb))[j4];
            float4 b5 = ((const float4*)(Bcol + (size_t)scol[e + 5] * ldb))[j4];
            float4 b6 = ((const float4*)(Bcol + (size_t)scol[e + 6] * ldb))[j4];
            float4 b7 = ((const float4*)(Bcol + (size_t)scol[e + 7] * ldb))[j4];
            a.x += v0 * b0.x + v1 * b1.x + v2 * b2.x + v3 * b3.x;
            a.y += v0 * b0.y + v1 * b1.y + v2 * b2.y + v3 * b3.y;
            a.z += v0 * b0.z + v1 * b1.z + v2 * b2.z + v3 * b3.z;
            a.w += v0 * b0.w + v1 * b1.w + v2 * b2.w + v3 * b3.w;
            acc1.x += v4 * b4.x + v5 * b5.x + v6 * b6.x + v7 * b7.x;
            acc1.y += v4 * b4.y + v5 * b5.y + v6 * b6.y + v7 * b7.y;
            acc1.z += v4 * b4.z + v5 * b5.z + v6 * b6.z + v7 * b7.z;
            acc1.w += v4 * b4.w + v5 * b5.w + v6 * b6.w + v7 * b7.w;
        }
        for (; e < nz; ++e) {
            float v = sval[e];
            float4 b = ((const float4*)(Bcol + (size_t)scol[e] * ldb))[j4];
            a.x += v * b.x; a.y += v * b.y; a.z += v * b.z; a.w += v * b.w;
        }
        a.x += acc1.x; a.y += acc1.y; a.z += acc1.z; a.w += acc1.w;
        if (i >= j0 && i < j0 + 4) ((float*)&a)[i - j0] = 0.0f;      // zero output diag
        *(float4*)(srow + j0) = a;
        psum += (a.x + a.y) + (a.z + a.w);
    }
    int lane = threadIdx.x & 63, w = threadIdx.x >> 6;
    for (int off = 32; off; off >>= 1) psum += __shfl_down(psum, off, 64);
    if (lane == 0) ssum[w] = psum;
    __syncthreads();
    if (w == 0) {
        if (lane == 0)
            dinvD[i] = rsqrtf((ssum[0] + ssum[1]) + (ssum[2] + ssum[3]) + 2.0f);
        int base = 0;
        for (int c0 = 0; c0 < kk; c0 += 64) {
            int c = c0 + lane;
            float v = (c < kk) ? srow[c] : 0.0f;
            unsigned long long mb = __ballot(v != 0.0f);
            if (v != 0.0f) {
                int idx = base + __popcll(mb & ((1ull << lane) - 1ull));
                if (idx < CAPD) {
                    colsD[(size_t)i * CAPD + idx] = c;
                    valsD[(size_t)i * CAPD + idx] = v;
                }
            }
            base += __popcll(mb);
        }
        if (lane == 0) cntD[i] = base < CAPD ? base : CAPD;
    }
}

// ---------------- launch ----------------

extern "C" void kernel_launch(void* const* d_in, const int* in_sizes, int n_in,
                              void* d_out, int out_size, void* d_ws, size_t ws_size,
                              hipStream_t stream) {
    const float* x   = (const float*)d_in[0];
    const int*   ei  = (const int*)d_in[1];
    const float* W0  = (const float*)d_in[2];
    const float* b0  = (const float*)d_in[3];
    const float* W1  = (const float*)d_in[4];
    const float* b1  = (const float*)d_in[5];
    const float* W2  = (const float*)d_in[6];
    const float* b2  = (const float*)d_in[7];
    const float* p1  = (const float*)d_in[8];
    const float* p2  = (const float*)d_in[9];
    const float* Wu0 = (const float*)d_in[10];
    const float* bu0 = (const float*)d_in[11];
    const float* Wu1 = (const float*)d_in[12];
    const float* bu1 = (const float*)d_in[13];
    float* out = (float*)d_out;

    // ---- workspace layout (float units) ----
    float* fw = (float*)d_ws;
    size_t off = 0;
    int*   slots  = (int*)(fw + off); off += (size_t)NN * SLOT;
    int*   cntraw = (int*)(fw + off); off += NN;
    int*   cols0  = (int*)(fw + off); off += (size_t)NN * CAP0;
    float* vals0  = fw + off;         off += (size_t)NN * CAP0;
    int*   cols1  = (int*)(fw + off); off += (size_t)KK1 * CAP1;
    float* vals1  = fw + off;         off += (size_t)KK1 * CAP1;
    int*   cols2  = (int*)(fw + off); off += (size_t)KK2 * CAP2;
    float* vals2  = fw + off;         off += (size_t)KK2 * CAP2;
    int*   bc0C   = (int*)(fw + off); off += (size_t)NN * CAPB0;
    float* bc0V   = fw + off;         off += (size_t)NN * CAPB0;
    int*   bc0N   = (int*)(fw + off); off += NN;
    float* Bcol2  = fw + off;         off += (size_t)KK1 * KK2P;
    int*   cnt0   = (int*)(fw + off); off += NN;
    int*   cnt1   = (int*)(fw + off); off += KK1;
    int*   cnt2   = (int*)(fw + off); off += KK2 + 2;
    float* g      = fw + off; off += (size_t)NN * HIDC;
    float* res0   = fw + off; off += (size_t)NN * HIDC;
    float* res1   = fw + off; off += (size_t)KK1 * HIDC;
    float* hp     = fw + off; off += (size_t)KK1 * HIDC;
    float* hp2    = fw + off; off += (size_t)KK2 * HIDC;
    float* x2     = fw + off; off += (size_t)KK2 * HIDC;
    float* xu     = fw + off; off += (size_t)KK1 * HIDC;
    float* sc1    = fw + off; off += NN;
    float* sc2    = fw + off; off += KK1;
    float* dinv0  = fw + off; off += NN;
    float* dinv1  = fw + off; off += KK1;
    float* dinv2  = fw + off; off += KK2 + 2;
    int* perm1    = (int*)(fw + off); off += KK1;
    int* perm2    = (int*)(fw + off); off += KK2 + 2;
    int* selpos1  = (int*)(fw + off); off += NN;
    int* selpos2  = (int*)(fw + off); off += KK1;
    if (ws_size < off * sizeof(float)) return;

    dim3 b64(64), b256(256);

    // ---- CSR0 + dinv0 directly from edge list
    hipMemsetAsync(cntraw, 0, NN * sizeof(int), stream);
    k_edge_slots<<<dim3((EE + 255) / 256), b256, 0, stream>>>(ei, cntraw, slots);
    k_csr0_sort<<<dim3(NN / 4), b256, 0, stream>>>(cntraw, slots, cols0, vals0, cnt0, dinv0);

    // ---- GCN0 -> res0 (+score sc1)
    k_xw_scale<<<dim3(NN), b64, 0, stream>>>(x, nullptr, nullptr, W0, dinv0, g, NN, 16, 64);
    k_gcn_agg_csr<<<dim3(NN), b256, 0, stream>>>(cols0, vals0, cnt0, CAP0, g, dinv0, b0, res0, NN, 64, 1, p1, sc1);

    // ---- pool 1 (topk + pool fused), then sparse augment -> CSR1 + dinv1
    k_topk<<<dim3(NN), b256, 0, stream>>>(sc1, res0, NN, KK1, perm1, selpos1, hp);
    k_bcolcsr<<<dim3(NN / 4), b256, 0, stream>>>(cols0, vals0, cnt0, CAP0, selpos1, NN, bc0C, bc0V, bc0N, CAPB0);
    k_aug_sparse<<<dim3(KK1), b256, 0, stream>>>(perm1, cols0, vals0, cnt0, CAP0,
                                                 bc0C, bc0V, bc0N, CAPB0, KK1,
                                                 cols1, vals1, cnt1, dinv1, CAP1);

    // ---- GCN1 -> res1 (+score sc2)
    k_xw_scale<<<dim3(KK1), b64, 0, stream>>>(hp, nullptr, nullptr, W1, dinv1, g, KK1, 64, 64);
    k_gcn_agg_csr<<<dim3(KK1), b256, 0, stream>>>(cols1, vals1, cnt1, CAP1, g, dinv1, b1, res1, KK1, 64, 1, p2, sc2);

    // ---- pool 2, dense-gather augment -> CSR2 + dinv2
    k_topk<<<dim3(KK1), b256, 0, stream>>>(sc2, res1, KK1, KK2, perm2, selpos2, hp2);
    hipMemsetAsync(Bcol2, 0, (size_t)KK1 * KK2P * sizeof(float), stream);
    k_bcol_scatter<<<dim3(KK1), b64, 0, stream>>>(cols1, vals1, cnt1, CAP1, selpos2, Bcol2, KK2P);
    k_aug_fused<<<dim3(KK2), b256, 0, stream>>>(perm2, cols1, vals1, cnt1, CAP1,
                                                Bcol2, KK2P, KK2, cols2, vals2, cnt2, dinv2, CAP2);

    // ---- GCN2 -> x2
    k_xw_scale<<<dim3(KK2), b64, 0, stream>>>(hp2, nullptr, nullptr, W2, dinv2, g, KK2, 64, 64);
    k_gcn_agg_csr<<<dim3(KK2), b256, 0, stream>>>(cols2, vals2, cnt2, CAP2, g, dinv2, b2, x2, KK2, 64, 1, nullptr, nullptr);

    // ---- up to level 1: h = res1 + up(x2 via selpos2); GCN(Wu0) -> xu
    k_xw_scale<<<dim3(KK1), b64, 0, stream>>>(res1, x2, selpos2, Wu0, dinv1, g, KK1, 64, 64);
    k_gcn_agg_csr<<<dim3(KK1), b256, 0, stream>>>(cols1, vals1, cnt1, CAP1, g, dinv1, bu0, xu, KK1, 64, 1, nullptr, nullptr);

    // ---- up to level 0: h = res0 + up(xu via selpos1); GCN(Wu1) -> out (no tanh)
    k_xw_scale<<<dim3(NN), b64, 0, stream>>>(res0, xu, selpos1, Wu1, dinv0, g, NN, 64, 16);
    k_gcn_agg_csr<<<dim3(NN), b256, 0, stream>>>(cols0, vals0, cnt0, CAP0, g, dinv0, bu1, out, NN, 16, 0, nullptr, nullptr);
}